// Round 8
// baseline (173.746 us; speedup 1.0000x reference)
//
#include <hip/hip_runtime.h>
#include <hip/hip_bf16.h>
#include <math.h>

#define T_SEQ 2048
#define HID 2048
#define HQ 16
#define HKV 8
#define D_HEAD 128
#define HALF 64
#define SCALE_F 0.08838834764831845f
#define PROJW 4096   // proj row width: q(2048) | k(1024) | v(1024)

typedef __attribute__((ext_vector_type(8))) short bf16x8;
typedef __attribute__((ext_vector_type(4))) float f32x4;

static __device__ __forceinline__ short f2bf(float x) {
  unsigned u = __builtin_bit_cast(unsigned, x);
  unsigned r = (u + 0x7FFF + ((u >> 16) & 1)) >> 16;   // RNE
  return (short)r;
}
static __device__ __forceinline__ float bf2f(unsigned short u) {
  unsigned v = ((unsigned)u) << 16;
  return __builtin_bit_cast(float, v);
}

#define GLDS(gsrc, ldst) \
  __builtin_amdgcn_global_load_lds((const __attribute__((address_space(1))) void*)(gsrc), \
                                   (__attribute__((address_space(3))) void*)(ldst), 16, 0, 0)

// ---------------- elementwise fp32 -> bf16 ----------------
__global__ __launch_bounds__(256)
void cvt_bf16(const float* __restrict__ in, short* __restrict__ out, int n4)
{
  int i = blockIdx.x * blockDim.x + threadIdx.x;
  if (i >= n4) return;
  float4 v = reinterpret_cast<const float4*>(in)[i];
  short4 o;
  o.x = f2bf(v.x); o.y = f2bf(v.y); o.z = f2bf(v.z); o.w = f2bf(v.w);
  reinterpret_cast<short4*>(out)[i] = o;
}

// ------- fused transpose of all 4 weights fp32[K][N] -> bf16[N][2048] -------
__global__ __launch_bounds__(256)
void transpose_all(const float* __restrict__ Wq, const float* __restrict__ Wk,
                   const float* __restrict__ Wv, const float* __restrict__ Wo,
                   short* __restrict__ BTall, short* __restrict__ WoT)
{
  const int bx = blockIdx.x;
  const int k0 = blockIdx.y * 32;
  const float* src; short* dst; int Nsrc, n0;
  if (bx < 64)       { src = Wq; Nsrc = 2048; dst = BTall;                       n0 = bx * 32; }
  else if (bx < 96)  { src = Wk; Nsrc = 1024; dst = BTall + (size_t)2048 * 2048; n0 = (bx - 64) * 32; }
  else if (bx < 128) { src = Wv; Nsrc = 1024; dst = BTall + (size_t)3072 * 2048; n0 = (bx - 96) * 32; }
  else               { src = Wo; Nsrc = 2048; dst = WoT;                         n0 = (bx - 128) * 32; }

  __shared__ float tile[32][33];
  const int r = threadIdx.x >> 5, c = threadIdx.x & 31;
  #pragma unroll
  for (int i = 0; i < 4; ++i)
    tile[r + i * 8][c] = src[(size_t)(k0 + r + i * 8) * Nsrc + n0 + c];
  __syncthreads();
  const int n = threadIdx.x >> 3, k4 = (threadIdx.x & 7) * 4;
  short4 o;
  o.x = f2bf(tile[k4 + 0][n]); o.y = f2bf(tile[k4 + 1][n]);
  o.z = f2bf(tile[k4 + 2][n]); o.w = f2bf(tile[k4 + 3][n]);
  *reinterpret_cast<short4*>(&dst[(size_t)(n0 + n) * 2048 + k0 + k4]) = o;
}

// ------------- pack concatenated bias [bq|bk|bv] -> bcat[4096] -------------
__global__ __launch_bounds__(256)
void pack_bias(const float* __restrict__ bq, const float* __restrict__ bk,
               const float* __restrict__ bv, float* __restrict__ bcat)
{
  const int i = blockIdx.x * 256 + threadIdx.x;
  bcat[i] = (i < 2048) ? bq[i] : ((i < 3072) ? bk[i - 2048] : bv[i - 3072]);
}

// ============ bf16 MFMA GEMM, 128Mx256N tile, BK=64, 8 waves ============
// Wave grid 2M x 4N, per-wave 64x64 (4x4 16x16 frags). LDS 96 KB:
// A[2][128][64], B[2][256][64], XOR-swizzled (byte ^= (row&7)<<4) via
// pre-swizzled global_load_lds sources (both-sides involution).
// Schedule per K-tile t (buf p=t&1): 2 phases (k-steps), staging tile t+1
// into buf p^1 spread over the phases; mid-tile barrier WITHOUT vmcnt
// (loads stay in flight), vmcnt(0)+barrier only at tile boundary.
// Race-free: reads of buf q retired (lgkm) before the barrier preceding
// any stage-issue into q; stage loads land before the vmcnt(0)+barrier
// that precedes reads of q.
template <bool OBF>
__global__ __launch_bounds__(512, 2)
void gemm_wide(const short* __restrict__ A, const short* __restrict__ BT,
               const float* __restrict__ bias, void* __restrict__ Cout,
               int N, int K)
{
  __shared__ __align__(16) char Alds[2][16384];
  __shared__ __align__(16) char Blds[2][32768];
  const int tid = threadIdx.x;
  const int wid = tid >> 6, lane = tid & 63;
  const int bm0 = blockIdx.y * 128, bn0 = blockIdx.x * 256;
  const int wr = wid >> 2, wc = wid & 3;
  const int c = lane & 15, g = lane >> 4;
  const int xv = (c & 7) << 4;

  f32x4 acc[4][4] = {};
  const int nk = K >> 6;

  // ---- staging: thread covers chunk ci = wid*64 + lane + j*512 ----
#define STG_A(buf, kt)                                                          \
  do {                                                                          \
    const int ci0 = wid * 64 + lane;                                            \
    const int r0 = ci0 >> 3, c0 = ((ci0 & 7) ^ (r0 & 7)) * 8;                   \
    GLDS(A + (size_t)(bm0 + r0) * K + (kt) * 64 + c0,                           \
         &Alds[buf][(wid * 64) * 16]);                                          \
    const int ci1 = ci0 + 512;                                                  \
    const int r1 = ci1 >> 3, c1 = ((ci1 & 7) ^ (r1 & 7)) * 8;                   \
    GLDS(A + (size_t)(bm0 + r1) * K + (kt) * 64 + c1,                           \
         &Alds[buf][(wid * 64 + 512) * 16]);                                    \
  } while (0)
#define STG_B(buf, kt, jj)                                                      \
  do {                                                                          \
    const int ci0 = wid * 64 + lane + (jj) * 512;                               \
    const int r0 = ci0 >> 3, c0 = ((ci0 & 7) ^ (r0 & 7)) * 8;                   \
    GLDS(BT + (size_t)(bn0 + r0) * K + (kt) * 64 + c0,                          \
         &Blds[buf][(wid * 64 + (jj) * 512) * 16]);                             \
    const int ci1 = ci0 + 512;                                                  \
    const int r1 = ci1 >> 3, c1 = ((ci1 & 7) ^ (r1 & 7)) * 8;                   \
    GLDS(BT + (size_t)(bn0 + r1) * K + (kt) * 64 + c1,                          \
         &Blds[buf][(wid * 64 + (jj) * 512 + 512) * 16]);                       \
  } while (0)

  // prologue: full tile 0, drain, publish
  STG_A(0, 0); STG_B(0, 0, 0); STG_B(0, 0, 2);
  asm volatile("s_waitcnt vmcnt(0)" ::: "memory");
  asm volatile("s_barrier" ::: "memory");
  __builtin_amdgcn_sched_barrier(0);

  for (int t = 0; t < nk; ++t) {
    const int p = t & 1, q = p ^ 1;
    const bool pre = (t + 1 < nk);

    // ---------- phase 0: k-step 0 ----------
    if (pre) { STG_A(q, t + 1); STG_B(q, t + 1, 0); }
    {
      bf16x8 a[4], b[4];
      #pragma unroll
      for (int m = 0; m < 4; ++m)
        a[m] = *reinterpret_cast<const bf16x8*>(
            &Alds[p][(((wr * 64 + m * 16 + c) * 128) + g * 16) ^ xv]);
      #pragma unroll
      for (int n = 0; n < 4; ++n)
        b[n] = *reinterpret_cast<const bf16x8*>(
            &Blds[p][(((wc * 64 + n * 16 + c) * 128) + g * 16) ^ xv]);
      __builtin_amdgcn_s_setprio(1);
      #pragma unroll
      for (int m = 0; m < 4; ++m)
        #pragma unroll
        for (int n = 0; n < 4; ++n)
          acc[m][n] = __builtin_amdgcn_mfma_f32_16x16x32_bf16(a[m], b[n], acc[m][n], 0, 0, 0);
      __builtin_amdgcn_s_setprio(0);
    }
    asm volatile("s_barrier" ::: "memory");     // mid-tile stagger, no vmcnt
    __builtin_amdgcn_sched_barrier(0);

    // ---------- phase 1: k-step 1 ----------
    if (pre) { STG_B(q, t + 1, 2); }
    {
      bf16x8 a[4], b[4];
      #pragma unroll
      for (int m = 0; m < 4; ++m)
        a[m] = *reinterpret_cast<const bf16x8*>(
            &Alds[p][(((wr * 64 + m * 16 + c) * 128) + 64 + g * 16) ^ xv]);
      #pragma unroll
      for (int n = 0; n < 4; ++n)
        b[n] = *reinterpret_cast<const bf16x8*>(
            &Blds[p][(((wc * 64 + n * 16 + c) * 128) + 64 + g * 16) ^ xv]);
      __builtin_amdgcn_s_setprio(1);
      #pragma unroll
      for (int m = 0; m < 4; ++m)
        #pragma unroll
        for (int n = 0; n < 4; ++n)
          acc[m][n] = __builtin_amdgcn_mfma_f32_16x16x32_bf16(a[m], b[n], acc[m][n], 0, 0, 0);
      __builtin_amdgcn_s_setprio(0);
    }
    if (pre) asm volatile("s_waitcnt vmcnt(0)" ::: "memory");  // next tile landed
    asm volatile("s_barrier" ::: "memory");
    __builtin_amdgcn_sched_barrier(0);
  }

  // epilogue
  const int crow = wr * 64 + g * 4;
  const int ccol = wc * 64 + c;
  #pragma unroll
  for (int j = 0; j < 4; ++j) {
    const int col = bn0 + ccol + j * 16;
    const float b = bias[col];
    #pragma unroll
    for (int i = 0; i < 4; ++i)
      #pragma unroll
      for (int r = 0; r < 4; ++r) {
        const int row = bm0 + crow + i * 16 + r;
        const float v = acc[i][j][r] + b;
        if constexpr (OBF)
          ((short*)Cout)[(size_t)row * N + col] = f2bf(v);
        else
          ((float*)Cout)[(size_t)row * N + col] = v;
      }
  }
#undef STG_A
#undef STG_B
}

// ------------- gate projection + log-sigmoid fused -------------
__global__ __launch_bounds__(256)
void gproj_kernel(const float* __restrict__ hs, const float* __restrict__ Wg,
                  const float* __restrict__ bg, float* __restrict__ gT)
{
  const int t = blockIdx.x, tid = threadIdx.x;
  __shared__ float red[256][9];
  float a[8] = {0.f, 0.f, 0.f, 0.f, 0.f, 0.f, 0.f, 0.f};
  for (int cc = tid; cc < HID; cc += 256) {
    const float hv = hs[(size_t)t * HID + cc];
    const float4 w0 = *reinterpret_cast<const float4*>(Wg + (size_t)cc * 8);
    const float4 w1 = *reinterpret_cast<const float4*>(Wg + (size_t)cc * 8 + 4);
    a[0] = fmaf(hv, w0.x, a[0]); a[1] = fmaf(hv, w0.y, a[1]);
    a[2] = fmaf(hv, w0.z, a[2]); a[3] = fmaf(hv, w0.w, a[3]);
    a[4] = fmaf(hv, w1.x, a[4]); a[5] = fmaf(hv, w1.y, a[5]);
    a[6] = fmaf(hv, w1.z, a[6]); a[7] = fmaf(hv, w1.w, a[7]);
  }
  #pragma unroll
  for (int j = 0; j < 8; ++j) red[tid][j] = a[j];
  __syncthreads();
  for (int s = 128; s >= 1; s >>= 1) {
    if (tid < s) {
      #pragma unroll
      for (int j = 0; j < 8; ++j) red[tid][j] += red[tid + s][j];
    }
    __syncthreads();
  }
  if (tid < 8) {
    const float x = red[0][tid] + bg[tid];
    const float nx = -x;
    const float sp = (nx > 20.f) ? nx : log1pf(expf(nx));
    gT[(size_t)tid * T_SEQ + t] = -sp;      // log_sigmoid(x)
  }
}

// ------- parallel inclusive cumsum over T per head -------
__global__ __launch_bounds__(512)
void gscan_kernel(const float* __restrict__ gT, float* __restrict__ Gct)
{
  const int h = blockIdx.x;
  const int tid = threadIdx.x;
  const int wid = tid >> 6, lane = tid & 63;
  __shared__ float wsum[8];

  const float4 v = reinterpret_cast<const float4*>(gT + (size_t)h * T_SEQ)[tid];
  const float p0 = v.x, p1 = p0 + v.y, p2 = p1 + v.z, p3 = p2 + v.w;

  float sc = p3;
  #pragma unroll
  for (int off = 1; off < 64; off <<= 1) {
    const float o = __shfl_up(sc, off, 64);
    if (lane >= off) sc += o;
  }
  if (lane == 63) wsum[wid] = sc;
  __syncthreads();
  float wof = 0.f;
  #pragma unroll
  for (int w = 0; w < 8; ++w) wof += (w < wid) ? wsum[w] : 0.f;

  const float excl = wof + sc - p3;
  reinterpret_cast<float4*>(Gct + (size_t)h * T_SEQ)[tid] =
      make_float4(excl + p0, excl + p1, excl + p2, excl + p3);
}

// ---------------- RoPE (NeoX) in place on proj (q + k regions) ----------------
__global__ __launch_bounds__(192)
void rope_kernel(short* __restrict__ proj)
{
  const int t = blockIdx.x;
  __shared__ float cs[64], sn[64];
  if (threadIdx.x < 64) {
    const int i = threadIdx.x;
    const float f = (float)t * powf(10000.0f, -(float)i / 64.0f);
    cs[i] = cosf(f); sn[i] = sinf(f);
  }
  __syncthreads();
  const int u = threadIdx.x;          // 24 heads x 8 chunks
  const int hh = u >> 3, ch = u & 7;
  short* base = proj + (size_t)t * PROJW +
                ((hh < HQ) ? hh * D_HEAD : 2048 + (hh - HQ) * D_HEAD);
  bf16x8 x1 = *reinterpret_cast<bf16x8*>(base + ch * 8);
  bf16x8 x2 = *reinterpret_cast<bf16x8*>(base + HALF + ch * 8);
  #pragma unroll
  for (int j = 0; j < 8; ++j) {
    const float a = bf2f((unsigned short)x1[j]);
    const float b = bf2f((unsigned short)x2[j]);
    const float cc = cs[ch * 8 + j], ss = sn[ch * 8 + j];
    x1[j] = f2bf(a * cc - b * ss);
    x2[j] = f2bf(b * cc + a * ss);
  }
  *reinterpret_cast<bf16x8*>(base + ch * 8) = x1;
  *reinterpret_cast<bf16x8*>(base + HALF + ch * 8) = x2;
}

// -------- V transpose: proj[t][3072 + hk*128 + d] -> Vt[hk][d][t] (bf16) --------
__global__ __launch_bounds__(256)
void vtrans_kernel(const unsigned short* __restrict__ proj, unsigned short* __restrict__ vt)
{
  __shared__ unsigned short tile[32][33];
  const int tt = blockIdx.x * 32, dd = blockIdx.y * 32, hk = blockIdx.z;
  const int c = threadIdx.x & 31, r0 = (threadIdx.x >> 5) * 4;
  #pragma unroll
  for (int i = 0; i < 4; ++i)
    tile[r0 + i][c] = proj[(size_t)(tt + r0 + i) * PROJW + 3072 + hk * 128 + dd + c];
  __syncthreads();
  #pragma unroll
  for (int i = 0; i < 4; ++i)
    vt[(size_t)(hk * 128 + dd + r0 + i) * T_SEQ + tt + c] = tile[c][r0 + i];
}

// ---------------- MFMA attention ----------------
__global__ __launch_bounds__(256, 1)
void attn_mfma(const short* __restrict__ proj, const short* __restrict__ vt,
               const float* __restrict__ Gct, short* __restrict__ outb)
{
  __shared__ __align__(16) char smem[86528];
  const int hk = blockIdx.x;
  const int tb = blockIdx.y * 64;
  const int tid = threadIdx.x;
  const int wid = tid >> 6, lane = tid & 63;
  const int c = lane & 15, g = lane >> 4;
  const int h = 2 * hk + (wid >> 1);
  const int tw = tb + (wid & 1) * 32;
  const float* Gh = Gct + (size_t)hk * T_SEQ;

  const float glim = Gh[tb] + 90.0f;
  int lo = 0, hi = tb;
  while (lo < hi) {
    const int mid = (lo + hi) >> 1;
    if (Gh[mid] > glim) lo = mid + 1; else hi = mid;
  }
  const int sfirst = lo & ~63;
  const int nst = ((tb - sfirst) >> 6) + 1;

  bf16x8 qf[2][4];
  #pragma unroll
  for (int tt = 0; tt < 2; ++tt)
    #pragma unroll
    for (int kb = 0; kb < 4; ++kb)
      qf[tt][kb] = *reinterpret_cast<const bf16x8*>(
          proj + (size_t)(tw + 16 * tt + c) * PROJW + h * D_HEAD + kb * 32 + g * 8);
  const float gt0 = Gh[tw + c];
  const float gt1 = Gh[tw + 16 + c];
  const float gtw = Gh[tw];
  const int twmax = tw + 31;

  f32x4 accv[2][8] = {};

#define ASTG(buf, s64)                                                                   \
  do {                                                                                   \
    _Pragma("unroll")                                                                    \
    for (int i2 = 0; i2 < 4; ++i2) {                                                     \
      const int cid = tid + 256 * i2;                                                    \
      const int kr = cid >> 4, kc = cid & 15;                                            \
      GLDS(proj + (size_t)((s64) + kr) * PROJW + 2048 + hk * 128 + ((kc ^ (kr & 7)) * 8),\
           smem + (buf) * 16384 + cid * 16);                                             \
      const int vr = cid >> 3, vc = cid & 7;                                             \
      GLDS(vt + (size_t)(hk * 128 + vr) * T_SEQ + (s64) + ((vc ^ (vr & 7)) * 8),         \
           smem + 32768 + (buf) * 16384 + cid * 16);                                     \
    }                                                                                    \
    if (tid < 64) ((float*)(smem + 86016))[(buf) * 64 + tid] = Gh[(s64) + tid];          \
  } while (0)

  ASTG(0, sfirst);
  __syncthreads();

  for (int i = 0; i < nst; ++i) {
    const int cur = i & 1;
    if (i + 1 < nst) ASTG(cur ^ 1, sfirst + (i + 1) * 64);
    const int sbase64 = sfirst + i * 64;
    const float* Gss = (const float*)(smem + 86016) + cur * 64;
    char* Pmy = smem + 65536 + wid * 5120;

    #pragma unroll
    for (int st = 0; st < 2; ++st) {
      const int s0 = sbase64 + st * 32;
      if (s0 > twmax) continue;
      if (gtw - Gss[st * 32 + 31] < -90.0f) continue;

      bf16x8 kf[2][4];
      #pragma unroll
      for (int sg = 0; sg < 2; ++sg)
        #pragma unroll
        for (int kb = 0; kb < 4; ++kb) {
          const int row = st * 32 + 16 * sg + c;
          const int byt = (row * 256 + kb * 64 + g * 16) ^ ((c & 7) << 4);
          kf[sg][kb] = *reinterpret_cast<const bf16x8*>(smem + cur * 16384 + byt);
        }
      f32x4 sa[2][2] = {};
      #pragma unroll
      for (int kb = 0; kb < 4; ++kb)
        #pragma unroll
        for (int sg = 0; sg < 2; ++sg)
          #pragma unroll
          for (int tt = 0; tt < 2; ++tt)
            sa[sg][tt] = __builtin_amdgcn_mfma_f32_16x16x32_bf16(
                kf[sg][kb], qf[tt][kb], sa[sg][tt], 0, 0, 0);

      #pragma unroll
      for (int sg = 0; sg < 2; ++sg) {
        const float4 gs = *reinterpret_cast<const float4*>(&Gss[st * 32 + sg * 16 + g * 4]);
        const float gsv[4] = {gs.x, gs.y, gs.z, gs.w};
        #pragma unroll
        for (int tt = 0; tt < 2; ++tt) {
          const int tg = tw + 16 * tt + c;
          const float gt = tt ? gt1 : gt0;
          const int sg0 = s0 + sg * 16 + g * 4;
          float w[4];
          #pragma unroll
          for (int r = 0; r < 4; ++r) {
            const float dv = sa[sg][tt][r] * SCALE_F;
            const float ww = dv * dv * __expf(gt - gsv[r]);
            w[r] = (sg0 + r <= tg) ? ww : 0.0f;
          }
          uint2 pv;
          pv.x = ((unsigned)(unsigned short)f2bf(w[1]) << 16) | (unsigned short)f2bf(w[0]);
          pv.y = ((unsigned)(unsigned short)f2bf(w[3]) << 16) | (unsigned short)f2bf(w[2]);
          *reinterpret_cast<uint2*>(Pmy + st * 2560 + (c + 16 * tt) * 80 + 8 * g + 32 * sg) = pv;
        }
      }
      asm volatile("s_waitcnt lgkmcnt(0)" ::: "memory");
      __builtin_amdgcn_sched_barrier(0);

      bf16x8 pf[2];
      #pragma unroll
      for (int tt = 0; tt < 2; ++tt)
        pf[tt] = *reinterpret_cast<const bf16x8*>(Pmy + st * 2560 + (c + 16 * tt) * 80 + g * 16);

      #pragma unroll
      for (int db = 0; db < 8; ++db) {
        const int row = 16 * db + c;
        const int byt = (row * 128 + st * 64 + g * 16) ^ ((c & 7) << 4);
        const bf16x8 vf = *reinterpret_cast<const bf16x8*>(smem + 32768 + cur * 16384 + byt);
        #pragma unroll
        for (int tt = 0; tt < 2; ++tt)
          accv[tt][db] = __builtin_amdgcn_mfma_f32_16x16x32_bf16(pf[tt], vf, accv[tt][db], 0, 0, 0);
      }
    }
    __syncthreads();
  }

  char* Wme = smem + wid * 8704;
  #pragma unroll
  for (int tt = 0; tt < 2; ++tt)
    #pragma unroll
    for (int db = 0; db < 8; ++db)
      #pragma unroll
      for (int r = 0; r < 4; ++r)
        *reinterpret_cast<short*>(Wme + (16 * tt + 4 * g + r) * 272 + (16 * db + c) * 2)
            = f2bf(accv[tt][db][r]);
  asm volatile("s_waitcnt lgkmcnt(0)" ::: "memory");
  __builtin_amdgcn_sched_barrier(0);
  #pragma unroll
  for (int e = 0; e < 8; ++e) {
    const int idx = e * 64 + lane;
    const int tr = idx >> 4, d0 = (idx & 15) * 8;
    const bf16x8 vv = *reinterpret_cast<const bf16x8*>(Wme + tr * 272 + d0 * 2);
    *reinterpret_cast<bf16x8*>(outb + ((size_t)(tw + tr) * HQ + h) * D_HEAD + d0) = vv;
  }
#undef ASTG
}

extern "C" void kernel_launch(void* const* d_in, const int* in_sizes, int n_in,
                              void* d_out, int out_size, void* d_ws, size_t ws_size,
                              hipStream_t stream)
{
  const float* hs = (const float*)d_in[1];
  const float* Wq = (const float*)d_in[2];
  const float* bq = (const float*)d_in[3];
  const float* Wk = (const float*)d_in[4];
  const float* bk = (const float*)d_in[5];
  const float* Wv = (const float*)d_in[6];
  const float* bv = (const float*)d_in[7];
  const float* Wg = (const float*)d_in[8];
  const float* bg = (const float*)d_in[9];
  const float* Wo = (const float*)d_in[10];
  const float* bo = (const float*)d_in[11];
  float* outp = (float*)d_out;

  // workspace carve (~52.2 MB)
  short* proj  = (short*)d_ws;                    // [T][4096] bf16 (q|k|v)   16 MB
  short* vtb   = proj + (size_t)T_SEQ * PROJW;    // [8][128][T] bf16          4 MB
  float* gT    = (float*)(vtb + (size_t)HKV * D_HEAD * T_SEQ);
  float* Gct   = gT + 16384;
  float* bcat  = Gct + 16384;                     // [4096] f32
  short* hsb   = (short*)(bcat + 4096);           // [T][2048] bf16            8 MB
  short* BTall = hsb + (size_t)2048 * 2048;       // [4096][2048] bf16        16 MB
  short* WoT   = BTall + (size_t)4096 * 2048;     // [2048][2048] bf16         8 MB
  short* attnout = hsb;                           // alias: hsb dead after QKV GEMM

  // 1) prep
  cvt_bf16<<<4096, 256, 0, stream>>>(hs, hsb, 1048576);
  transpose_all<<<dim3(192, 64), 256, 0, stream>>>(Wq, Wk, Wv, Wo, BTall, WoT);
  pack_bias<<<16, 256, 0, stream>>>(bq, bk, bv, bcat);

  // 2) gate + scan
  gproj_kernel<<<2048, 256, 0, stream>>>(hs, Wg, bg, gT);
  gscan_kernel<<<8, 512, 0, stream>>>(gT, Gct);

  // 3) fused QKV projection: 16x16 = 256 blocks, 512 threads
  gemm_wide<true><<<dim3(16, 16), 512, 0, stream>>>(
      hsb, BTall, bcat, proj, PROJW, 2048);

  // 4) RoPE + V transpose
  rope_kernel<<<2048, 192, 0, stream>>>(proj);
  vtrans_kernel<<<dim3(64, 4, 8), 256, 0, stream>>>((const unsigned short*)proj,
                                                    (unsigned short*)vtb);

  // 5) attention -> bf16 into hsb region
  attn_mfma<<<dim3(8, 32), 256, 0, stream>>>(proj, vtb, Gct, attnout);

  // 6) output projection: 8x16 = 128 blocks
  gemm_wide<false><<<dim3(8, 16), 512, 0, stream>>>(
      attnout, WoT, bo, outp, 2048, 2048);
}

// Round 9
// 145.695 us; speedup vs baseline: 1.1925x; 1.1925x over previous
//
#include <hip/hip_runtime.h>
#include <hip/hip_bf16.h>
#include <math.h>

#define T_SEQ 2048
#define HID 2048
#define HQ 16
#define HKV 8
#define D_HEAD 128
#define HALF 64
#define SCALE_F 0.08838834764831845f
#define PROJW 4096   // proj row width: q(2048) | k(1024) | v(1024)

typedef __attribute__((ext_vector_type(8))) short bf16x8;
typedef __attribute__((ext_vector_type(4))) float f32x4;

static __device__ __forceinline__ short f2bf(float x) {
  unsigned u = __builtin_bit_cast(unsigned, x);
  unsigned r = (u + 0x7FFF + ((u >> 16) & 1)) >> 16;   // RNE
  return (short)r;
}
static __device__ __forceinline__ float bf2f(unsigned short u) {
  unsigned v = ((unsigned)u) << 16;
  return __builtin_bit_cast(float, v);
}

#define GLDS(gsrc, ldst) \
  __builtin_amdgcn_global_load_lds((const __attribute__((address_space(1))) void*)(gsrc), \
                                   (__attribute__((address_space(3))) void*)(ldst), 16, 0, 0)

// ---------------- elementwise fp32 -> bf16 ----------------
__global__ __launch_bounds__(256)
void cvt_bf16(const float* __restrict__ in, short* __restrict__ out, int n4)
{
  int i = blockIdx.x * blockDim.x + threadIdx.x;
  if (i >= n4) return;
  float4 v = reinterpret_cast<const float4*>(in)[i];
  short4 o;
  o.x = f2bf(v.x); o.y = f2bf(v.y); o.z = f2bf(v.z); o.w = f2bf(v.w);
  reinterpret_cast<short4*>(out)[i] = o;
}

// ------- fused transpose of all 4 weights fp32[K][N] -> bf16[N][2048] -------
__global__ __launch_bounds__(256)
void transpose_all(const float* __restrict__ Wq, const float* __restrict__ Wk,
                   const float* __restrict__ Wv, const float* __restrict__ Wo,
                   short* __restrict__ BTall, short* __restrict__ WoT)
{
  const int bx = blockIdx.x;
  const int k0 = blockIdx.y * 32;
  const float* src; short* dst; int Nsrc, n0;
  if (bx < 64)       { src = Wq; Nsrc = 2048; dst = BTall;                       n0 = bx * 32; }
  else if (bx < 96)  { src = Wk; Nsrc = 1024; dst = BTall + (size_t)2048 * 2048; n0 = (bx - 64) * 32; }
  else if (bx < 128) { src = Wv; Nsrc = 1024; dst = BTall + (size_t)3072 * 2048; n0 = (bx - 96) * 32; }
  else               { src = Wo; Nsrc = 2048; dst = WoT;                         n0 = (bx - 128) * 32; }

  __shared__ float tile[32][33];
  const int r = threadIdx.x >> 5, c = threadIdx.x & 31;
  #pragma unroll
  for (int i = 0; i < 4; ++i)
    tile[r + i * 8][c] = src[(size_t)(k0 + r + i * 8) * Nsrc + n0 + c];
  __syncthreads();
  const int n = threadIdx.x >> 3, k4 = (threadIdx.x & 7) * 4;
  short4 o;
  o.x = f2bf(tile[k4 + 0][n]); o.y = f2bf(tile[k4 + 1][n]);
  o.z = f2bf(tile[k4 + 2][n]); o.w = f2bf(tile[k4 + 3][n]);
  *reinterpret_cast<short4*>(&dst[(size_t)(n0 + n) * 2048 + k0 + k4]) = o;
}

// ------------- pack concatenated bias [bq|bk|bv] -> bcat[4096] -------------
__global__ __launch_bounds__(256)
void pack_bias(const float* __restrict__ bq, const float* __restrict__ bk,
               const float* __restrict__ bv, float* __restrict__ bcat)
{
  const int i = blockIdx.x * 256 + threadIdx.x;
  bcat[i] = (i < 2048) ? bq[i] : ((i < 3072) ? bk[i - 2048] : bv[i - 3072]);
}

// ---------------- fp32 add: out += part ----------------
__global__ __launch_bounds__(256)
void add_f32(float* __restrict__ out, const float* __restrict__ part, int n4)
{
  int i = blockIdx.x * blockDim.x + threadIdx.x;
  if (i >= n4) return;
  float4 a = reinterpret_cast<float4*>(out)[i];
  const float4 b = reinterpret_cast<const float4*>(part)[i];
  a.x += b.x; a.y += b.y; a.z += b.z; a.w += b.w;
  reinterpret_cast<float4*>(out)[i] = a;
}

// ============ bf16 MFMA GEMM, phase-interleaved counted-vmcnt schedule ============
// BM=256, BN=128, BK=64; 512 threads = 8 waves (4M x 2N), wave tile 64x64
// (4x4 16x16x32 frags). LDS: 3 buffers A[256][64] + B[128][64] bf16 = 144 KB,
// XOR-swizzled (byte ^= (row&7)<<4) via pre-swizzled global_load_lds sources.
// Per K-tile t (buf t%3): 4 snake-quadrant phases (8 MFMA each, 16 ds_read per
// 32 MFMA via operand reuse). Staging of tile t+2 goes to buf (t+2)%3 — a
// buffer whose reads finished at tile t-1 (disjoint from both live buffers).
// ONE counted s_waitcnt vmcnt(6) per tile boundary (in-flight = next tile's 6
// loads, issued a full tile earlier); vmcnt(0) only at the last prefetch tile.
// split-K via blockIdx.z: z==0 -> Cout0 (+bias), z>0 -> Cout1 (no bias).
template <bool OBF>
__global__ __launch_bounds__(512, 1)
void gemm8p(const short* __restrict__ A, const short* __restrict__ BT,
            const float* __restrict__ bias, void* __restrict__ Cout0,
            void* __restrict__ Cout1, int N, int Kst, int klen)
{
  __shared__ __align__(16) short Al[3][256 * 64];
  __shared__ __align__(16) short Bl[3][128 * 64];
  const int tid = threadIdx.x, wid = tid >> 6, lane = tid & 63;
  const int z = blockIdx.z;
  const int koff = z * klen;
  // bijective XCD swizzle within the z-plane (plane size % 8 == 0)
  const int nwg = gridDim.x * gridDim.y;
  const int orig = blockIdx.y * gridDim.x + blockIdx.x;
  const int swz = (orig & 7) * (nwg >> 3) + (orig >> 3);
  const int bx = swz % gridDim.x, by = swz / gridDim.x;
  const int bm0 = by * 256, bn0 = bx * 128;
  const int wr = wid >> 1, wc = wid & 1;           // wave tile origin (64x64)
  const int c = lane & 15, g = lane >> 4;
  const int xc = (c & 7) << 4;                     // read-side swizzle (bytes)
  const int nk = klen >> 6;

  f32x4 acc[4][4] = {};

  // staging round j: 512 chunks of 16B, chunk cid -> row cid>>3, slot cid&7;
  // source column-chunk pre-swizzled so linear LDS + swizzled read match.
#define STGA(p, kt, j) do {                                                   \
    const int cid = (j) * 512 + wid * 64 + lane;                              \
    const int rr = cid >> 3;                                                  \
    const int gx = (cid & 7) ^ (rr & 7);                                      \
    GLDS(A + (size_t)(bm0 + rr) * Kst + koff + (kt) * 64 + gx * 8,            \
         &Al[p][((j) * 512 + wid * 64) * 8]);                                 \
  } while (0)
#define STGB(p, kt, j) do {                                                   \
    const int cid = (j) * 512 + wid * 64 + lane;                              \
    const int rr = cid >> 3;                                                  \
    const int gx = (cid & 7) ^ (rr & 7);                                      \
    GLDS(BT + (size_t)(bn0 + rr) * Kst + koff + (kt) * 64 + gx * 8,           \
         &Bl[p][((j) * 512 + wid * 64) * 8]);                                 \
  } while (0)

  // swizzled LDS fragment reads (row&7 == c&7 since bases are 0 mod 8)
#define RDA(p, mh, mm, ks)                                                    \
  (*reinterpret_cast<const bf16x8*>((const char*)&Al[p][0] +                  \
      (size_t)(wr * 64 + (mh) * 32 + (mm) * 16 + c) * 128 +                   \
      (((ks) * 64 + g * 16) ^ xc)))
#define RDB(p, nh, nn, ks)                                                    \
  (*reinterpret_cast<const bf16x8*>((const char*)&Bl[p][0] +                  \
      (size_t)(wc * 64 + (nh) * 32 + (nn) * 16 + c) * 128 +                   \
      (((ks) * 64 + g * 16) ^ xc)))

  // prologue: stage tiles 0 and 1 fully; retire tile 0 (counted), publish
  STGA(0, 0, 0); STGA(0, 0, 1); STGA(0, 0, 2); STGA(0, 0, 3);
  STGB(0, 0, 0); STGB(0, 0, 1);
  if (nk > 1) {
    STGA(1, 1, 0); STGA(1, 1, 1); STGA(1, 1, 2); STGA(1, 1, 3);
    STGB(1, 1, 0); STGB(1, 1, 1);
    asm volatile("s_waitcnt vmcnt(6)" ::: "memory");
  } else {
    asm volatile("s_waitcnt vmcnt(0)" ::: "memory");
  }
  __builtin_amdgcn_s_barrier();
  __builtin_amdgcn_sched_barrier(0);

  bf16x8 aR[2][2], b0R[2][2], b1R[2][2];

  for (int t = 0; t < nk; ++t) {
    const int p = t % 3;
    const int s2 = (t + 2) % 3;
    const bool pre = (t + 2 < nk);

    // ---- phase 0: quadrant (mh0, nh0) ----
    #pragma unroll
    for (int mm = 0; mm < 2; ++mm) { aR[mm][0] = RDA(p, 0, mm, 0); aR[mm][1] = RDA(p, 0, mm, 1); }
    #pragma unroll
    for (int nn = 0; nn < 2; ++nn) { b0R[nn][0] = RDB(p, 0, nn, 0); b0R[nn][1] = RDB(p, 0, nn, 1); }
    if (pre) { STGA(s2, t + 2, 0); STGA(s2, t + 2, 1); }
    __builtin_amdgcn_s_barrier();
    asm volatile("s_waitcnt lgkmcnt(0)" ::: "memory");
    __builtin_amdgcn_sched_barrier(0);
    __builtin_amdgcn_s_setprio(1);
    #pragma unroll
    for (int ks = 0; ks < 2; ++ks)
      #pragma unroll
      for (int mm = 0; mm < 2; ++mm)
        #pragma unroll
        for (int nn = 0; nn < 2; ++nn)
          acc[mm][nn] = __builtin_amdgcn_mfma_f32_16x16x32_bf16(aR[mm][ks], b0R[nn][ks], acc[mm][nn], 0, 0, 0);
    __builtin_amdgcn_s_setprio(0);
    __builtin_amdgcn_s_barrier();

    // ---- phase 1: quadrant (mh0, nh1) ----
    #pragma unroll
    for (int nn = 0; nn < 2; ++nn) { b1R[nn][0] = RDB(p, 1, nn, 0); b1R[nn][1] = RDB(p, 1, nn, 1); }
    if (pre) { STGA(s2, t + 2, 2); STGA(s2, t + 2, 3); }
    __builtin_amdgcn_s_barrier();
    asm volatile("s_waitcnt lgkmcnt(0)" ::: "memory");
    __builtin_amdgcn_sched_barrier(0);
    __builtin_amdgcn_s_setprio(1);
    #pragma unroll
    for (int ks = 0; ks < 2; ++ks)
      #pragma unroll
      for (int mm = 0; mm < 2; ++mm)
        #pragma unroll
        for (int nn = 0; nn < 2; ++nn)
          acc[mm][2 + nn] = __builtin_amdgcn_mfma_f32_16x16x32_bf16(aR[mm][ks], b1R[nn][ks], acc[mm][2 + nn], 0, 0, 0);
    __builtin_amdgcn_s_setprio(0);
    __builtin_amdgcn_s_barrier();

    // ---- phase 2: quadrant (mh1, nh1) ----
    #pragma unroll
    for (int mm = 0; mm < 2; ++mm) { aR[mm][0] = RDA(p, 1, mm, 0); aR[mm][1] = RDA(p, 1, mm, 1); }
    if (pre) STGB(s2, t + 2, 0);
    __builtin_amdgcn_s_barrier();
    asm volatile("s_waitcnt lgkmcnt(0)" ::: "memory");
    __builtin_amdgcn_sched_barrier(0);
    __builtin_amdgcn_s_setprio(1);
    #pragma unroll
    for (int ks = 0; ks < 2; ++ks)
      #pragma unroll
      for (int mm = 0; mm < 2; ++mm)
        #pragma unroll
        for (int nn = 0; nn < 2; ++nn)
          acc[2 + mm][2 + nn] = __builtin_amdgcn_mfma_f32_16x16x32_bf16(aR[mm][ks], b1R[nn][ks], acc[2 + mm][2 + nn], 0, 0, 0);
    __builtin_amdgcn_s_setprio(0);
    __builtin_amdgcn_s_barrier();

    // ---- phase 3: quadrant (mh1, nh0), reuse aR + b0R ----
    if (pre) STGB(s2, t + 2, 1);
    __builtin_amdgcn_s_barrier();
    __builtin_amdgcn_sched_barrier(0);
    __builtin_amdgcn_s_setprio(1);
    #pragma unroll
    for (int ks = 0; ks < 2; ++ks)
      #pragma unroll
      for (int mm = 0; mm < 2; ++mm)
        #pragma unroll
        for (int nn = 0; nn < 2; ++nn)
          acc[2 + mm][nn] = __builtin_amdgcn_mfma_f32_16x16x32_bf16(aR[mm][ks], b0R[nn][ks], acc[2 + mm][nn], 0, 0, 0);
    __builtin_amdgcn_s_setprio(0);
    // tile boundary: retire next tile's loads (counted; 0 only at the tail)
    if (pre)                asm volatile("s_waitcnt vmcnt(6)" ::: "memory");
    else if (t + 1 < nk)    asm volatile("s_waitcnt vmcnt(0)" ::: "memory");
    __builtin_amdgcn_s_barrier();
    __builtin_amdgcn_sched_barrier(0);
  }

  // epilogue
  void* Cout = (z == 0) ? Cout0 : Cout1;
  const int crow = bm0 + wr * 64 + g * 4;
  const int ccol = bn0 + wc * 64 + c;
  #pragma unroll
  for (int nf = 0; nf < 4; ++nf) {
    const int col = ccol + nf * 16;
    const float b = (z == 0) ? bias[col] : 0.f;
    #pragma unroll
    for (int mf = 0; mf < 4; ++mf)
      #pragma unroll
      for (int rr = 0; rr < 4; ++rr) {
        const int row = crow + mf * 16 + rr;
        const float v = acc[mf][nf][rr] + b;
        if constexpr (OBF)
          ((short*)Cout)[(size_t)row * N + col] = f2bf(v);
        else
          ((float*)Cout)[(size_t)row * N + col] = v;
      }
  }
#undef STGA
#undef STGB
#undef RDA
#undef RDB
}

// ------------- gate projection + log-sigmoid fused -------------
__global__ __launch_bounds__(256)
void gproj_kernel(const float* __restrict__ hs, const float* __restrict__ Wg,
                  const float* __restrict__ bg, float* __restrict__ gT)
{
  const int t = blockIdx.x, tid = threadIdx.x;
  __shared__ float red[256][9];
  float a[8] = {0.f, 0.f, 0.f, 0.f, 0.f, 0.f, 0.f, 0.f};
  for (int cc = tid; cc < HID; cc += 256) {
    const float hv = hs[(size_t)t * HID + cc];
    const float4 w0 = *reinterpret_cast<const float4*>(Wg + (size_t)cc * 8);
    const float4 w1 = *reinterpret_cast<const float4*>(Wg + (size_t)cc * 8 + 4);
    a[0] = fmaf(hv, w0.x, a[0]); a[1] = fmaf(hv, w0.y, a[1]);
    a[2] = fmaf(hv, w0.z, a[2]); a[3] = fmaf(hv, w0.w, a[3]);
    a[4] = fmaf(hv, w1.x, a[4]); a[5] = fmaf(hv, w1.y, a[5]);
    a[6] = fmaf(hv, w1.z, a[6]); a[7] = fmaf(hv, w1.w, a[7]);
  }
  #pragma unroll
  for (int j = 0; j < 8; ++j) red[tid][j] = a[j];
  __syncthreads();
  for (int s = 128; s >= 1; s >>= 1) {
    if (tid < s) {
      #pragma unroll
      for (int j = 0; j < 8; ++j) red[tid][j] += red[tid + s][j];
    }
    __syncthreads();
  }
  if (tid < 8) {
    const float x = red[0][tid] + bg[tid];
    const float nx = -x;
    const float sp = (nx > 20.f) ? nx : log1pf(expf(nx));
    gT[(size_t)tid * T_SEQ + t] = -sp;      // log_sigmoid(x)
  }
}

// ------- parallel inclusive cumsum over T per head -------
__global__ __launch_bounds__(512)
void gscan_kernel(const float* __restrict__ gT, float* __restrict__ Gct)
{
  const int h = blockIdx.x;
  const int tid = threadIdx.x;
  const int wid = tid >> 6, lane = tid & 63;
  __shared__ float wsum[8];

  const float4 v = reinterpret_cast<const float4*>(gT + (size_t)h * T_SEQ)[tid];
  const float p0 = v.x, p1 = p0 + v.y, p2 = p1 + v.z, p3 = p2 + v.w;

  float sc = p3;
  #pragma unroll
  for (int off = 1; off < 64; off <<= 1) {
    const float o = __shfl_up(sc, off, 64);
    if (lane >= off) sc += o;
  }
  if (lane == 63) wsum[wid] = sc;
  __syncthreads();
  float wof = 0.f;
  #pragma unroll
  for (int w = 0; w < 8; ++w) wof += (w < wid) ? wsum[w] : 0.f;

  const float excl = wof + sc - p3;
  reinterpret_cast<float4*>(Gct + (size_t)h * T_SEQ)[tid] =
      make_float4(excl + p0, excl + p1, excl + p2, excl + p3);
}

// ---------------- RoPE (NeoX) in place on proj (q + k regions) ----------------
__global__ __launch_bounds__(192)
void rope_kernel(short* __restrict__ proj)
{
  const int t = blockIdx.x;
  __shared__ float cs[64], sn[64];
  if (threadIdx.x < 64) {
    const int i = threadIdx.x;
    const float f = (float)t * powf(10000.0f, -(float)i / 64.0f);
    cs[i] = cosf(f); sn[i] = sinf(f);
  }
  __syncthreads();
  const int u = threadIdx.x;          // 24 heads x 8 chunks
  const int hh = u >> 3, ch = u & 7;
  short* base = proj + (size_t)t * PROJW +
                ((hh < HQ) ? hh * D_HEAD : 2048 + (hh - HQ) * D_HEAD);
  bf16x8 x1 = *reinterpret_cast<bf16x8*>(base + ch * 8);
  bf16x8 x2 = *reinterpret_cast<bf16x8*>(base + HALF + ch * 8);
  #pragma unroll
  for (int j = 0; j < 8; ++j) {
    const float a = bf2f((unsigned short)x1[j]);
    const float b = bf2f((unsigned short)x2[j]);
    const float cc = cs[ch * 8 + j], ss = sn[ch * 8 + j];
    x1[j] = f2bf(a * cc - b * ss);
    x2[j] = f2bf(b * cc + a * ss);
  }
  *reinterpret_cast<bf16x8*>(base + ch * 8) = x1;
  *reinterpret_cast<bf16x8*>(base + HALF + ch * 8) = x2;
}

// -------- V transpose: proj[t][3072 + hk*128 + d] -> Vt[hk][d][t] (bf16) --------
__global__ __launch_bounds__(256)
void vtrans_kernel(const unsigned short* __restrict__ proj, unsigned short* __restrict__ vt)
{
  __shared__ unsigned short tile[32][33];
  const int tt = blockIdx.x * 32, dd = blockIdx.y * 32, hk = blockIdx.z;
  const int c = threadIdx.x & 31, r0 = (threadIdx.x >> 5) * 4;
  #pragma unroll
  for (int i = 0; i < 4; ++i)
    tile[r0 + i][c] = proj[(size_t)(tt + r0 + i) * PROJW + 3072 + hk * 128 + dd + c];
  __syncthreads();
  #pragma unroll
  for (int i = 0; i < 4; ++i)
    vt[(size_t)(hk * 128 + dd + r0 + i) * T_SEQ + tt + c] = tile[c][r0 + i];
}

// ---------------- MFMA attention ----------------
__global__ __launch_bounds__(256, 1)
void attn_mfma(const short* __restrict__ proj, const short* __restrict__ vt,
               const float* __restrict__ Gct, short* __restrict__ outb)
{
  __shared__ __align__(16) char smem[86528];
  const int hk = blockIdx.x;
  const int tb = blockIdx.y * 64;
  const int tid = threadIdx.x;
  const int wid = tid >> 6, lane = tid & 63;
  const int c = lane & 15, g = lane >> 4;
  const int h = 2 * hk + (wid >> 1);
  const int tw = tb + (wid & 1) * 32;
  const float* Gh = Gct + (size_t)hk * T_SEQ;

  const float glim = Gh[tb] + 90.0f;
  int lo = 0, hi = tb;
  while (lo < hi) {
    const int mid = (lo + hi) >> 1;
    if (Gh[mid] > glim) lo = mid + 1; else hi = mid;
  }
  const int sfirst = lo & ~63;
  const int nst = ((tb - sfirst) >> 6) + 1;

  bf16x8 qf[2][4];
  #pragma unroll
  for (int tt = 0; tt < 2; ++tt)
    #pragma unroll
    for (int kb = 0; kb < 4; ++kb)
      qf[tt][kb] = *reinterpret_cast<const bf16x8*>(
          proj + (size_t)(tw + 16 * tt + c) * PROJW + h * D_HEAD + kb * 32 + g * 8);
  const float gt0 = Gh[tw + c];
  const float gt1 = Gh[tw + 16 + c];
  const float gtw = Gh[tw];
  const int twmax = tw + 31;

  f32x4 accv[2][8] = {};

#define ASTG(buf, s64)                                                                   \
  do {                                                                                   \
    _Pragma("unroll")                                                                    \
    for (int i2 = 0; i2 < 4; ++i2) {                                                     \
      const int cid = tid + 256 * i2;                                                    \
      const int kr = cid >> 4, kc = cid & 15;                                            \
      GLDS(proj + (size_t)((s64) + kr) * PROJW + 2048 + hk * 128 + ((kc ^ (kr & 7)) * 8),\
           smem + (buf) * 16384 + cid * 16);                                             \
      const int vr = cid >> 3, vc = cid & 7;                                             \
      GLDS(vt + (size_t)(hk * 128 + vr) * T_SEQ + (s64) + ((vc ^ (vr & 7)) * 8),         \
           smem + 32768 + (buf) * 16384 + cid * 16);                                     \
    }                                                                                    \
    if (tid < 64) ((float*)(smem + 86016))[(buf) * 64 + tid] = Gh[(s64) + tid];          \
  } while (0)

  ASTG(0, sfirst);
  __syncthreads();

  for (int i = 0; i < nst; ++i) {
    const int cur = i & 1;
    if (i + 1 < nst) ASTG(cur ^ 1, sfirst + (i + 1) * 64);
    const int sbase64 = sfirst + i * 64;
    const float* Gss = (const float*)(smem + 86016) + cur * 64;
    char* Pmy = smem + 65536 + wid * 5120;

    #pragma unroll
    for (int st = 0; st < 2; ++st) {
      const int s0 = sbase64 + st * 32;
      if (s0 > twmax) continue;
      if (gtw - Gss[st * 32 + 31] < -90.0f) continue;

      bf16x8 kf[2][4];
      #pragma unroll
      for (int sg = 0; sg < 2; ++sg)
        #pragma unroll
        for (int kb = 0; kb < 4; ++kb) {
          const int row = st * 32 + 16 * sg + c;
          const int byt = (row * 256 + kb * 64 + g * 16) ^ ((c & 7) << 4);
          kf[sg][kb] = *reinterpret_cast<const bf16x8*>(smem + cur * 16384 + byt);
        }
      f32x4 sa[2][2] = {};
      #pragma unroll
      for (int kb = 0; kb < 4; ++kb)
        #pragma unroll
        for (int sg = 0; sg < 2; ++sg)
          #pragma unroll
          for (int tt = 0; tt < 2; ++tt)
            sa[sg][tt] = __builtin_amdgcn_mfma_f32_16x16x32_bf16(
                kf[sg][kb], qf[tt][kb], sa[sg][tt], 0, 0, 0);

      #pragma unroll
      for (int sg = 0; sg < 2; ++sg) {
        const float4 gs = *reinterpret_cast<const float4*>(&Gss[st * 32 + sg * 16 + g * 4]);
        const float gsv[4] = {gs.x, gs.y, gs.z, gs.w};
        #pragma unroll
        for (int tt = 0; tt < 2; ++tt) {
          const int tg = tw + 16 * tt + c;
          const float gt = tt ? gt1 : gt0;
          const int sg0 = s0 + sg * 16 + g * 4;
          float w[4];
          #pragma unroll
          for (int r = 0; r < 4; ++r) {
            const float dv = sa[sg][tt][r] * SCALE_F;
            const float ww = dv * dv * __expf(gt - gsv[r]);
            w[r] = (sg0 + r <= tg) ? ww : 0.0f;
          }
          uint2 pv;
          pv.x = ((unsigned)(unsigned short)f2bf(w[1]) << 16) | (unsigned short)f2bf(w[0]);
          pv.y = ((unsigned)(unsigned short)f2bf(w[3]) << 16) | (unsigned short)f2bf(w[2]);
          *reinterpret_cast<uint2*>(Pmy + st * 2560 + (c + 16 * tt) * 80 + 8 * g + 32 * sg) = pv;
        }
      }
      asm volatile("s_waitcnt lgkmcnt(0)" ::: "memory");
      __builtin_amdgcn_sched_barrier(0);

      bf16x8 pf[2];
      #pragma unroll
      for (int tt = 0; tt < 2; ++tt)
        pf[tt] = *reinterpret_cast<const bf16x8*>(Pmy + st * 2560 + (c + 16 * tt) * 80 + g * 16);

      #pragma unroll
      for (int db = 0; db < 8; ++db) {
        const int row = 16 * db + c;
        const int byt = (row * 128 + st * 64 + g * 16) ^ ((c & 7) << 4);
        const bf16x8 vf = *reinterpret_cast<const bf16x8*>(smem + 32768 + cur * 16384 + byt);
        #pragma unroll
        for (int tt = 0; tt < 2; ++tt)
          accv[tt][db] = __builtin_amdgcn_mfma_f32_16x16x32_bf16(pf[tt], vf, accv[tt][db], 0, 0, 0);
      }
    }
    __syncthreads();
  }

  char* Wme = smem + wid * 8704;
  #pragma unroll
  for (int tt = 0; tt < 2; ++tt)
    #pragma unroll
    for (int db = 0; db < 8; ++db)
      #pragma unroll
      for (int r = 0; r < 4; ++r)
        *reinterpret_cast<short*>(Wme + (16 * tt + 4 * g + r) * 272 + (16 * db + c) * 2)
            = f2bf(accv[tt][db][r]);
  asm volatile("s_waitcnt lgkmcnt(0)" ::: "memory");
  __builtin_amdgcn_sched_barrier(0);
  #pragma unroll
  for (int e = 0; e < 8; ++e) {
    const int idx = e * 64 + lane;
    const int tr = idx >> 4, d0 = (idx & 15) * 8;
    const bf16x8 vv = *reinterpret_cast<const bf16x8*>(Wme + tr * 272 + d0 * 2);
    *reinterpret_cast<bf16x8*>(outb + ((size_t)(tw + tr) * HQ + h) * D_HEAD + d0) = vv;
  }
#undef ASTG
}

extern "C" void kernel_launch(void* const* d_in, const int* in_sizes, int n_in,
                              void* d_out, int out_size, void* d_ws, size_t ws_size,
                              hipStream_t stream)
{
  const float* hs = (const float*)d_in[1];
  const float* Wq = (const float*)d_in[2];
  const float* bq = (const float*)d_in[3];
  const float* Wk = (const float*)d_in[4];
  const float* bk = (const float*)d_in[5];
  const float* Wv = (const float*)d_in[6];
  const float* bv = (const float*)d_in[7];
  const float* Wg = (const float*)d_in[8];
  const float* bg = (const float*)d_in[9];
  const float* Wo = (const float*)d_in[10];
  const float* bo = (const float*)d_in[11];
  float* outp = (float*)d_out;

  // workspace carve (~52.2 MB)
  short* proj  = (short*)d_ws;                    // [T][4096] bf16 (q|k|v)   16 MB
  short* vtb   = proj + (size_t)T_SEQ * PROJW;    // [8][128][T] bf16          4 MB
  float* gT    = (float*)(vtb + (size_t)HKV * D_HEAD * T_SEQ);
  float* Gct   = gT + 16384;
  float* bcat  = Gct + 16384;                     // [4096] f32
  short* hsb   = (short*)(bcat + 4096);           // [T][2048] bf16            8 MB
  short* BTall = hsb + (size_t)2048 * 2048;       // [4096][2048] bf16        16 MB
  short* WoT   = BTall + (size_t)4096 * 2048;     // [2048][2048] bf16         8 MB
  short* attnout = hsb;                           // alias: hsb dead after QKV GEMM
  float* opart   = (float*)BTall;                 // alias: BTall dead after QKV GEMM (16 MB)

  // 1) prep
  cvt_bf16<<<4096, 256, 0, stream>>>(hs, hsb, 1048576);
  transpose_all<<<dim3(192, 64), 256, 0, stream>>>(Wq, Wk, Wv, Wo, BTall, WoT);
  pack_bias<<<16, 256, 0, stream>>>(bq, bk, bv, bcat);

  // 2) gate + scan
  gproj_kernel<<<2048, 256, 0, stream>>>(hs, Wg, bg, gT);
  gscan_kernel<<<8, 512, 0, stream>>>(gT, Gct);

  // 3) fused QKV projection: 256x128 tiles -> 8x32 = 256 blocks (1/CU)
  gemm8p<true><<<dim3(32, 8, 1), 512, 0, stream>>>(
      hsb, BTall, bcat, proj, proj, PROJW, 2048, 2048);

  // 4) RoPE + V transpose
  rope_kernel<<<2048, 192, 0, stream>>>(proj);
  vtrans_kernel<<<dim3(64, 4, 8), 256, 0, stream>>>((const unsigned short*)proj,
                                                    (unsigned short*)vtb);

  // 5) attention -> bf16 into hsb region
  attn_mfma<<<dim3(8, 32), 256, 0, stream>>>(proj, vtb, Gct, attnout);

  // 6) output projection, split-K=2: 16x8x2 = 256 blocks; z=1 partial into
  //    the dead BTall region, then fold.
  gemm8p<false><<<dim3(16, 8, 2), 512, 0, stream>>>(
      attnout, WoT, bo, outp, opart, 2048, 2048, 1024);
  add_f32<<<4096, 256, 0, stream>>>(outp, opart, 1048576);
}

// Round 10
// 143.100 us; speedup vs baseline: 1.2142x; 1.0181x over previous
//
#include <hip/hip_runtime.h>
#include <hip/hip_bf16.h>
#include <math.h>

#define T_SEQ 2048
#define HID 2048
#define HQ 16
#define HKV 8
#define D_HEAD 128
#define HALF 64
#define SCALE_F 0.08838834764831845f
#define PROJW 4096   // proj row width: q(2048) | k(1024) | v(1024)

typedef __attribute__((ext_vector_type(8))) short bf16x8;
typedef __attribute__((ext_vector_type(4))) float f32x4;

static __device__ __forceinline__ short f2bf(float x) {
  unsigned u = __builtin_bit_cast(unsigned, x);
  unsigned r = (u + 0x7FFF + ((u >> 16) & 1)) >> 16;   // RNE
  return (short)r;
}
static __device__ __forceinline__ float bf2f(unsigned short u) {
  unsigned v = ((unsigned)u) << 16;
  return __builtin_bit_cast(float, v);
}

#define GLDS(gsrc, ldst) \
  __builtin_amdgcn_global_load_lds((const __attribute__((address_space(1))) void*)(gsrc), \
                                   (__attribute__((address_space(3))) void*)(ldst), 16, 0, 0)

// ---------------- elementwise fp32 -> bf16 ----------------
__global__ __launch_bounds__(256)
void cvt_bf16(const float* __restrict__ in, short* __restrict__ out, int n4)
{
  int i = blockIdx.x * blockDim.x + threadIdx.x;
  if (i >= n4) return;
  float4 v = reinterpret_cast<const float4*>(in)[i];
  short4 o;
  o.x = f2bf(v.x); o.y = f2bf(v.y); o.z = f2bf(v.z); o.w = f2bf(v.w);
  reinterpret_cast<short4*>(out)[i] = o;
}

// ------- fused transpose of all 4 weights fp32[K][N] -> bf16[N][2048] -------
__global__ __launch_bounds__(256)
void transpose_all(const float* __restrict__ Wq, const float* __restrict__ Wk,
                   const float* __restrict__ Wv, const float* __restrict__ Wo,
                   short* __restrict__ BTall, short* __restrict__ WoT)
{
  const int bx = blockIdx.x;
  const int k0 = blockIdx.y * 32;
  const float* src; short* dst; int Nsrc, n0;
  if (bx < 64)       { src = Wq; Nsrc = 2048; dst = BTall;                       n0 = bx * 32; }
  else if (bx < 96)  { src = Wk; Nsrc = 1024; dst = BTall + (size_t)2048 * 2048; n0 = (bx - 64) * 32; }
  else if (bx < 128) { src = Wv; Nsrc = 1024; dst = BTall + (size_t)3072 * 2048; n0 = (bx - 96) * 32; }
  else               { src = Wo; Nsrc = 2048; dst = WoT;                         n0 = (bx - 128) * 32; }

  __shared__ float tile[32][33];
  const int r = threadIdx.x >> 5, c = threadIdx.x & 31;
  #pragma unroll
  for (int i = 0; i < 4; ++i)
    tile[r + i * 8][c] = src[(size_t)(k0 + r + i * 8) * Nsrc + n0 + c];
  __syncthreads();
  const int n = threadIdx.x >> 3, k4 = (threadIdx.x & 7) * 4;
  short4 o;
  o.x = f2bf(tile[k4 + 0][n]); o.y = f2bf(tile[k4 + 1][n]);
  o.z = f2bf(tile[k4 + 2][n]); o.w = f2bf(tile[k4 + 3][n]);
  *reinterpret_cast<short4*>(&dst[(size_t)(n0 + n) * 2048 + k0 + k4]) = o;
}

// ------------- pack concatenated bias [bq|bk|bv] -> bcat[4096] -------------
__global__ __launch_bounds__(256)
void pack_bias(const float* __restrict__ bq, const float* __restrict__ bk,
               const float* __restrict__ bv, float* __restrict__ bcat)
{
  const int i = blockIdx.x * 256 + threadIdx.x;
  bcat[i] = (i < 2048) ? bq[i] : ((i < 3072) ? bk[i - 2048] : bv[i - 3072]);
}

// ---------------- fp32 add: out += part ----------------
__global__ __launch_bounds__(256)
void add_f32(float* __restrict__ out, const float* __restrict__ part, int n4)
{
  int i = blockIdx.x * blockDim.x + threadIdx.x;
  if (i >= n4) return;
  float4 a = reinterpret_cast<float4*>(out)[i];
  const float4 b = reinterpret_cast<const float4*>(part)[i];
  a.x += b.x; a.y += b.y; a.z += b.z; a.w += b.w;
  reinterpret_cast<float4*>(out)[i] = a;
}

// ============ bf16 MFMA GEMM, 3-buffer counted-vmcnt, single barrier/tile ============
// BM=256, BN=128, BK=64; 512 threads = 8 waves (4M x 2N), wave tile 64x64
// (4x4 16x16x32 frags). LDS: 3 buffers A[256][64] + B[128][64] bf16 = 144 KB,
// XOR-swizzled (byte ^= (row&7)<<4) via pre-swizzled global_load_lds sources.
// Per K-tile t (read buf t%3): issue 6 staging gloads for tile t+2 into buf
// (t+2)%3 (always disjoint from both live buffers), issue 16 ds_read_b128,
// lgkmcnt(0), 32-MFMA cluster, then ONE boundary sync: s_waitcnt vmcnt(6)
// (retires tile t+1's data; 6 newest in flight = tile t+2's loads) + s_barrier.
// vmcnt(0) only when tile t+2 doesn't exist (tail). Race-free: buf b's reads
// are lgkm-retired before the boundary barrier that precedes any re-staging
// of b; cross-wave staging visibility = per-wave counted vmcnt + barrier.
// split-K via blockIdx.z: z==0 -> Cout0 (+bias), z>0 -> Cout1 (no bias).
template <bool OBF>
__global__ __launch_bounds__(512, 1)
void gemm8p(const short* __restrict__ A, const short* __restrict__ BT,
            const float* __restrict__ bias, void* __restrict__ Cout0,
            void* __restrict__ Cout1, int N, int Kst, int klen)
{
  __shared__ __align__(16) short Al[3][256 * 64];
  __shared__ __align__(16) short Bl[3][128 * 64];
  const int tid = threadIdx.x, wid = tid >> 6, lane = tid & 63;
  const int z = blockIdx.z;
  const int koff = z * klen;
  // bijective XCD swizzle within the z-plane (plane size % 8 == 0)
  const int nwg = gridDim.x * gridDim.y;
  const int orig = blockIdx.y * gridDim.x + blockIdx.x;
  const int swz = (orig & 7) * (nwg >> 3) + (orig >> 3);
  const int bx = swz % gridDim.x, by = swz / gridDim.x;
  const int bm0 = by * 256, bn0 = bx * 128;
  const int wr = wid >> 1, wc = wid & 1;           // wave tile origin (64x64)
  const int c = lane & 15, g = lane >> 4;
  const int xc = (c & 7) << 4;                     // read-side swizzle (bytes)
  const int nk = klen >> 6;

  f32x4 acc[4][4] = {};

  // staging round j: 512 chunks of 16B, chunk cid -> row cid>>3, slot cid&7;
  // source column-chunk pre-swizzled so linear LDS + swizzled read match.
#define STGA(p, kt, j) do {                                                   \
    const int cid = (j) * 512 + wid * 64 + lane;                              \
    const int rr = cid >> 3;                                                  \
    const int gx = (cid & 7) ^ (rr & 7);                                      \
    GLDS(A + (size_t)(bm0 + rr) * Kst + koff + (kt) * 64 + gx * 8,            \
         &Al[p][((j) * 512 + wid * 64) * 8]);                                 \
  } while (0)
#define STGB(p, kt, j) do {                                                   \
    const int cid = (j) * 512 + wid * 64 + lane;                              \
    const int rr = cid >> 3;                                                  \
    const int gx = (cid & 7) ^ (rr & 7);                                      \
    GLDS(BT + (size_t)(bn0 + rr) * Kst + koff + (kt) * 64 + gx * 8,           \
         &Bl[p][((j) * 512 + wid * 64) * 8]);                                 \
  } while (0)

  // swizzled LDS fragment reads (frag row mf*16+c, k-slot ks)
#define RDA2(p, mf, ks)                                                       \
  (*reinterpret_cast<const bf16x8*>((const char*)&Al[p][0] +                  \
      (size_t)(wr * 64 + (mf) * 16 + c) * 128 + (((ks) * 64 + g * 16) ^ xc)))
#define RDB2(p, nf, ks)                                                       \
  (*reinterpret_cast<const bf16x8*>((const char*)&Bl[p][0] +                  \
      (size_t)(wc * 64 + (nf) * 16 + c) * 128 + (((ks) * 64 + g * 16) ^ xc)))

  // prologue: stage tiles 0 and 1 fully; retire tile 0 (counted), publish
  STGA(0, 0, 0); STGA(0, 0, 1); STGA(0, 0, 2); STGA(0, 0, 3);
  STGB(0, 0, 0); STGB(0, 0, 1);
  if (nk > 1) {
    STGA(1, 1, 0); STGA(1, 1, 1); STGA(1, 1, 2); STGA(1, 1, 3);
    STGB(1, 1, 0); STGB(1, 1, 1);
    asm volatile("s_waitcnt vmcnt(6)" ::: "memory");
  } else {
    asm volatile("s_waitcnt vmcnt(0)" ::: "memory");
  }
  __builtin_amdgcn_s_barrier();
  __builtin_amdgcn_sched_barrier(0);

  for (int t = 0; t < nk; ++t) {
    const int p = t % 3;
    const int s2 = (t + 2) % 3;

    // 1) issue staging for tile t+2 (overlaps everything below)
    if (t + 2 < nk) {
      STGA(s2, t + 2, 0); STGA(s2, t + 2, 1); STGA(s2, t + 2, 2); STGA(s2, t + 2, 3);
      STGB(s2, t + 2, 0); STGB(s2, t + 2, 1);
    }

    // 2) issue all fragment reads for this tile
    bf16x8 aR[4][2], bR[4][2];
    #pragma unroll
    for (int mf = 0; mf < 4; ++mf) {
      aR[mf][0] = RDA2(p, mf, 0); aR[mf][1] = RDA2(p, mf, 1);
    }
    #pragma unroll
    for (int nf = 0; nf < 4; ++nf) {
      bR[nf][0] = RDB2(p, nf, 0); bR[nf][1] = RDB2(p, nf, 1);
    }
    asm volatile("s_waitcnt lgkmcnt(0)" ::: "memory");
    __builtin_amdgcn_sched_barrier(0);

    // 3) MFMA cluster
    __builtin_amdgcn_s_setprio(1);
    #pragma unroll
    for (int ks = 0; ks < 2; ++ks)
      #pragma unroll
      for (int mf = 0; mf < 4; ++mf)
        #pragma unroll
        for (int nf = 0; nf < 4; ++nf)
          acc[mf][nf] = __builtin_amdgcn_mfma_f32_16x16x32_bf16(
              aR[mf][ks], bR[nf][ks], acc[mf][nf], 0, 0, 0);
    __builtin_amdgcn_s_setprio(0);

    // 4) single boundary sync: counted vmcnt (never 0 in steady state) + barrier
    if (t + 1 < nk) {
      if (t + 2 < nk) asm volatile("s_waitcnt vmcnt(6)" ::: "memory");
      else            asm volatile("s_waitcnt vmcnt(0)" ::: "memory");
      __builtin_amdgcn_s_barrier();
      __builtin_amdgcn_sched_barrier(0);
    }
  }

  // epilogue
  void* Cout = (z == 0) ? Cout0 : Cout1;
  const int crow = bm0 + wr * 64 + g * 4;
  const int ccol = bn0 + wc * 64 + c;
  #pragma unroll
  for (int nf = 0; nf < 4; ++nf) {
    const int col = ccol + nf * 16;
    const float b = (z == 0) ? bias[col] : 0.f;
    #pragma unroll
    for (int mf = 0; mf < 4; ++mf)
      #pragma unroll
      for (int rr = 0; rr < 4; ++rr) {
        const int row = crow + mf * 16 + rr;
        const float v = acc[mf][nf][rr] + b;
        if constexpr (OBF)
          ((short*)Cout)[(size_t)row * N + col] = f2bf(v);
        else
          ((float*)Cout)[(size_t)row * N + col] = v;
      }
  }
#undef STGA
#undef STGB
#undef RDA2
#undef RDB2
}

// ------------- gate projection + log-sigmoid fused -------------
__global__ __launch_bounds__(256)
void gproj_kernel(const float* __restrict__ hs, const float* __restrict__ Wg,
                  const float* __restrict__ bg, float* __restrict__ gT)
{
  const int t = blockIdx.x, tid = threadIdx.x;
  __shared__ float red[256][9];
  float a[8] = {0.f, 0.f, 0.f, 0.f, 0.f, 0.f, 0.f, 0.f};
  for (int cc = tid; cc < HID; cc += 256) {
    const float hv = hs[(size_t)t * HID + cc];
    const float4 w0 = *reinterpret_cast<const float4*>(Wg + (size_t)cc * 8);
    const float4 w1 = *reinterpret_cast<const float4*>(Wg + (size_t)cc * 8 + 4);
    a[0] = fmaf(hv, w0.x, a[0]); a[1] = fmaf(hv, w0.y, a[1]);
    a[2] = fmaf(hv, w0.z, a[2]); a[3] = fmaf(hv, w0.w, a[3]);
    a[4] = fmaf(hv, w1.x, a[4]); a[5] = fmaf(hv, w1.y, a[5]);
    a[6] = fmaf(hv, w1.z, a[6]); a[7] = fmaf(hv, w1.w, a[7]);
  }
  #pragma unroll
  for (int j = 0; j < 8; ++j) red[tid][j] = a[j];
  __syncthreads();
  for (int s = 128; s >= 1; s >>= 1) {
    if (tid < s) {
      #pragma unroll
      for (int j = 0; j < 8; ++j) red[tid][j] += red[tid + s][j];
    }
    __syncthreads();
  }
  if (tid < 8) {
    const float x = red[0][tid] + bg[tid];
    const float nx = -x;
    const float sp = (nx > 20.f) ? nx : log1pf(expf(nx));
    gT[(size_t)tid * T_SEQ + t] = -sp;      // log_sigmoid(x)
  }
}

// ------- parallel inclusive cumsum over T per head -------
__global__ __launch_bounds__(512)
void gscan_kernel(const float* __restrict__ gT, float* __restrict__ Gct)
{
  const int h = blockIdx.x;
  const int tid = threadIdx.x;
  const int wid = tid >> 6, lane = tid & 63;
  __shared__ float wsum[8];

  const float4 v = reinterpret_cast<const float4*>(gT + (size_t)h * T_SEQ)[tid];
  const float p0 = v.x, p1 = p0 + v.y, p2 = p1 + v.z, p3 = p2 + v.w;

  float sc = p3;
  #pragma unroll
  for (int off = 1; off < 64; off <<= 1) {
    const float o = __shfl_up(sc, off, 64);
    if (lane >= off) sc += o;
  }
  if (lane == 63) wsum[wid] = sc;
  __syncthreads();
  float wof = 0.f;
  #pragma unroll
  for (int w = 0; w < 8; ++w) wof += (w < wid) ? wsum[w] : 0.f;

  const float excl = wof + sc - p3;
  reinterpret_cast<float4*>(Gct + (size_t)h * T_SEQ)[tid] =
      make_float4(excl + p0, excl + p1, excl + p2, excl + p3);
}

// ---------------- RoPE (NeoX) in place on proj (q + k regions) ----------------
__global__ __launch_bounds__(192)
void rope_kernel(short* __restrict__ proj)
{
  const int t = blockIdx.x;
  __shared__ float cs[64], sn[64];
  if (threadIdx.x < 64) {
    const int i = threadIdx.x;
    const float f = (float)t * powf(10000.0f, -(float)i / 64.0f);
    cs[i] = cosf(f); sn[i] = sinf(f);
  }
  __syncthreads();
  const int u = threadIdx.x;          // 24 heads x 8 chunks
  const int hh = u >> 3, ch = u & 7;
  short* base = proj + (size_t)t * PROJW +
                ((hh < HQ) ? hh * D_HEAD : 2048 + (hh - HQ) * D_HEAD);
  bf16x8 x1 = *reinterpret_cast<bf16x8*>(base + ch * 8);
  bf16x8 x2 = *reinterpret_cast<bf16x8*>(base + HALF + ch * 8);
  #pragma unroll
  for (int j = 0; j < 8; ++j) {
    const float a = bf2f((unsigned short)x1[j]);
    const float b = bf2f((unsigned short)x2[j]);
    const float cc = cs[ch * 8 + j], ss = sn[ch * 8 + j];
    x1[j] = f2bf(a * cc - b * ss);
    x2[j] = f2bf(b * cc + a * ss);
  }
  *reinterpret_cast<bf16x8*>(base + ch * 8) = x1;
  *reinterpret_cast<bf16x8*>(base + HALF + ch * 8) = x2;
}

// -------- V transpose: proj[t][3072 + hk*128 + d] -> Vt[hk][d][t] (bf16) --------
__global__ __launch_bounds__(256)
void vtrans_kernel(const unsigned short* __restrict__ proj, unsigned short* __restrict__ vt)
{
  __shared__ unsigned short tile[32][33];
  const int tt = blockIdx.x * 32, dd = blockIdx.y * 32, hk = blockIdx.z;
  const int c = threadIdx.x & 31, r0 = (threadIdx.x >> 5) * 4;
  #pragma unroll
  for (int i = 0; i < 4; ++i)
    tile[r0 + i][c] = proj[(size_t)(tt + r0 + i) * PROJW + 3072 + hk * 128 + dd + c];
  __syncthreads();
  #pragma unroll
  for (int i = 0; i < 4; ++i)
    vt[(size_t)(hk * 128 + dd + r0 + i) * T_SEQ + tt + c] = tile[c][r0 + i];
}

// ---------------- MFMA attention ----------------
__global__ __launch_bounds__(256, 1)
void attn_mfma(const short* __restrict__ proj, const short* __restrict__ vt,
               const float* __restrict__ Gct, short* __restrict__ outb)
{
  __shared__ __align__(16) char smem[86528];
  const int hk = blockIdx.x;
  const int tb = blockIdx.y * 64;
  const int tid = threadIdx.x;
  const int wid = tid >> 6, lane = tid & 63;
  const int c = lane & 15, g = lane >> 4;
  const int h = 2 * hk + (wid >> 1);
  const int tw = tb + (wid & 1) * 32;
  const float* Gh = Gct + (size_t)hk * T_SEQ;

  const float glim = Gh[tb] + 90.0f;
  int lo = 0, hi = tb;
  while (lo < hi) {
    const int mid = (lo + hi) >> 1;
    if (Gh[mid] > glim) lo = mid + 1; else hi = mid;
  }
  const int sfirst = lo & ~63;
  const int nst = ((tb - sfirst) >> 6) + 1;

  bf16x8 qf[2][4];
  #pragma unroll
  for (int tt = 0; tt < 2; ++tt)
    #pragma unroll
    for (int kb = 0; kb < 4; ++kb)
      qf[tt][kb] = *reinterpret_cast<const bf16x8*>(
          proj + (size_t)(tw + 16 * tt + c) * PROJW + h * D_HEAD + kb * 32 + g * 8);
  const float gt0 = Gh[tw + c];
  const float gt1 = Gh[tw + 16 + c];
  const float gtw = Gh[tw];
  const int twmax = tw + 31;

  f32x4 accv[2][8] = {};

#define ASTG(buf, s64)                                                                   \
  do {                                                                                   \
    _Pragma("unroll")                                                                    \
    for (int i2 = 0; i2 < 4; ++i2) {                                                     \
      const int cid = tid + 256 * i2;                                                    \
      const int kr = cid >> 4, kc = cid & 15;                                            \
      GLDS(proj + (size_t)((s64) + kr) * PROJW + 2048 + hk * 128 + ((kc ^ (kr & 7)) * 8),\
           smem + (buf) * 16384 + cid * 16);                                             \
      const int vr = cid >> 3, vc = cid & 7;                                             \
      GLDS(vt + (size_t)(hk * 128 + vr) * T_SEQ + (s64) + ((vc ^ (vr & 7)) * 8),         \
           smem + 32768 + (buf) * 16384 + cid * 16);                                     \
    }                                                                                    \
    if (tid < 64) ((float*)(smem + 86016))[(buf) * 64 + tid] = Gh[(s64) + tid];          \
  } while (0)

  ASTG(0, sfirst);
  __syncthreads();

  for (int i = 0; i < nst; ++i) {
    const int cur = i & 1;
    if (i + 1 < nst) ASTG(cur ^ 1, sfirst + (i + 1) * 64);
    const int sbase64 = sfirst + i * 64;
    const float* Gss = (const float*)(smem + 86016) + cur * 64;
    char* Pmy = smem + 65536 + wid * 5120;

    #pragma unroll
    for (int st = 0; st < 2; ++st) {
      const int s0 = sbase64 + st * 32;
      if (s0 > twmax) continue;
      if (gtw - Gss[st * 32 + 31] < -90.0f) continue;

      bf16x8 kf[2][4];
      #pragma unroll
      for (int sg = 0; sg < 2; ++sg)
        #pragma unroll
        for (int kb = 0; kb < 4; ++kb) {
          const int row = st * 32 + 16 * sg + c;
          const int byt = (row * 256 + kb * 64 + g * 16) ^ ((c & 7) << 4);
          kf[sg][kb] = *reinterpret_cast<const bf16x8*>(smem + cur * 16384 + byt);
        }
      f32x4 sa[2][2] = {};
      #pragma unroll
      for (int kb = 0; kb < 4; ++kb)
        #pragma unroll
        for (int sg = 0; sg < 2; ++sg)
          #pragma unroll
          for (int tt = 0; tt < 2; ++tt)
            sa[sg][tt] = __builtin_amdgcn_mfma_f32_16x16x32_bf16(
                kf[sg][kb], qf[tt][kb], sa[sg][tt], 0, 0, 0);

      #pragma unroll
      for (int sg = 0; sg < 2; ++sg) {
        const float4 gs = *reinterpret_cast<const float4*>(&Gss[st * 32 + sg * 16 + g * 4]);
        const float gsv[4] = {gs.x, gs.y, gs.z, gs.w};
        #pragma unroll
        for (int tt = 0; tt < 2; ++tt) {
          const int tg = tw + 16 * tt + c;
          const float gt = tt ? gt1 : gt0;
          const int sg0 = s0 + sg * 16 + g * 4;
          float w[4];
          #pragma unroll
          for (int r = 0; r < 4; ++r) {
            const float dv = sa[sg][tt][r] * SCALE_F;
            const float ww = dv * dv * __expf(gt - gsv[r]);
            w[r] = (sg0 + r <= tg) ? ww : 0.0f;
          }
          uint2 pv;
          pv.x = ((unsigned)(unsigned short)f2bf(w[1]) << 16) | (unsigned short)f2bf(w[0]);
          pv.y = ((unsigned)(unsigned short)f2bf(w[3]) << 16) | (unsigned short)f2bf(w[2]);
          *reinterpret_cast<uint2*>(Pmy + st * 2560 + (c + 16 * tt) * 80 + 8 * g + 32 * sg) = pv;
        }
      }
      asm volatile("s_waitcnt lgkmcnt(0)" ::: "memory");
      __builtin_amdgcn_sched_barrier(0);

      bf16x8 pf[2];
      #pragma unroll
      for (int tt = 0; tt < 2; ++tt)
        pf[tt] = *reinterpret_cast<const bf16x8*>(Pmy + st * 2560 + (c + 16 * tt) * 80 + g * 16);

      #pragma unroll
      for (int db = 0; db < 8; ++db) {
        const int row = 16 * db + c;
        const int byt = (row * 128 + st * 64 + g * 16) ^ ((c & 7) << 4);
        const bf16x8 vf = *reinterpret_cast<const bf16x8*>(smem + 32768 + cur * 16384 + byt);
        #pragma unroll
        for (int tt = 0; tt < 2; ++tt)
          accv[tt][db] = __builtin_amdgcn_mfma_f32_16x16x32_bf16(pf[tt], vf, accv[tt][db], 0, 0, 0);
      }
    }
    __syncthreads();
  }

  char* Wme = smem + wid * 8704;
  #pragma unroll
  for (int tt = 0; tt < 2; ++tt)
    #pragma unroll
    for (int db = 0; db < 8; ++db)
      #pragma unroll
      for (int r = 0; r < 4; ++r)
        *reinterpret_cast<short*>(Wme + (16 * tt + 4 * g + r) * 272 + (16 * db + c) * 2)
            = f2bf(accv[tt][db][r]);
  asm volatile("s_waitcnt lgkmcnt(0)" ::: "memory");
  __builtin_amdgcn_sched_barrier(0);
  #pragma unroll
  for (int e = 0; e < 8; ++e) {
    const int idx = e * 64 + lane;
    const int tr = idx >> 4, d0 = (idx & 15) * 8;
    const bf16x8 vv = *reinterpret_cast<const bf16x8*>(Wme + tr * 272 + d0 * 2);
    *reinterpret_cast<bf16x8*>(outb + ((size_t)(tw + tr) * HQ + h) * D_HEAD + d0) = vv;
  }
#undef ASTG
}

extern "C" void kernel_launch(void* const* d_in, const int* in_sizes, int n_in,
                              void* d_out, int out_size, void* d_ws, size_t ws_size,
                              hipStream_t stream)
{
  const float* hs = (const float*)d_in[1];
  const float* Wq = (const float*)d_in[2];
  const float* bq = (const float*)d_in[3];
  const float* Wk = (const float*)d_in[4];
  const float* bk = (const float*)d_in[5];
  const float* Wv = (const float*)d_in[6];
  const float* bv = (const float*)d_in[7];
  const float* Wg = (const float*)d_in[8];
  const float* bg = (const float*)d_in[9];
  const float* Wo = (const float*)d_in[10];
  const float* bo = (const float*)d_in[11];
  float* outp = (float*)d_out;

  // workspace carve (~52.2 MB)
  short* proj  = (short*)d_ws;                    // [T][4096] bf16 (q|k|v)   16 MB
  short* vtb   = proj + (size_t)T_SEQ * PROJW;    // [8][128][T] bf16          4 MB
  float* gT    = (float*)(vtb + (size_t)HKV * D_HEAD * T_SEQ);
  float* Gct   = gT + 16384;
  float* bcat  = Gct + 16384;                     // [4096] f32
  short* hsb   = (short*)(bcat + 4096);           // [T][2048] bf16            8 MB
  short* BTall = hsb + (size_t)2048 * 2048;       // [4096][2048] bf16        16 MB
  short* WoT   = BTall + (size_t)4096 * 2048;     // [2048][2048] bf16         8 MB
  short* attnout = hsb;                           // alias: hsb dead after QKV GEMM
  float* opart   = (float*)BTall;                 // alias: BTall dead after QKV GEMM (16 MB)

  // 1) prep
  cvt_bf16<<<4096, 256, 0, stream>>>(hs, hsb, 1048576);
  transpose_all<<<dim3(192, 64), 256, 0, stream>>>(Wq, Wk, Wv, Wo, BTall, WoT);
  pack_bias<<<16, 256, 0, stream>>>(bq, bk, bv, bcat);

  // 2) gate + scan
  gproj_kernel<<<2048, 256, 0, stream>>>(hs, Wg, bg, gT);
  gscan_kernel<<<8, 512, 0, stream>>>(gT, Gct);

  // 3) fused QKV projection: 256x128 tiles -> 8x32 = 256 blocks (1/CU)
  gemm8p<true><<<dim3(32, 8, 1), 512, 0, stream>>>(
      hsb, BTall, bcat, proj, proj, PROJW, 2048, 2048);

  // 4) RoPE + V transpose
  rope_kernel<<<2048, 192, 0, stream>>>(proj);
  vtrans_kernel<<<dim3(64, 4, 8), 256, 0, stream>>>((const unsigned short*)proj,
                                                    (unsigned short*)vtb);

  // 5) attention -> bf16 into hsb region
  attn_mfma<<<dim3(8, 32), 256, 0, stream>>>(proj, vtb, Gct, attnout);

  // 6) output projection, split-K=2: 16x8x2 = 256 blocks; z=1 partial into
  //    the dead BTall region, then fold.
  gemm8p<false><<<dim3(16, 8, 2), 512, 0, stream>>>(
      attnout, WoT, bo, outp, opart, 2048, 2048, 1024);
  add_f32<<<4096, 256, 0, stream>>>(outp, opart, 1048576);
}

// Round 11
// 140.169 us; speedup vs baseline: 1.2396x; 1.0209x over previous
//
#include <hip/hip_runtime.h>
#include <hip/hip_bf16.h>
#include <math.h>

#define T_SEQ 2048
#define HID 2048
#define HQ 16
#define HKV 8
#define D_HEAD 128
#define HALF 64
#define SCALE_F 0.08838834764831845f
#define PROJW 4096   // proj row width: q(2048) | k(1024) | v(1024)

typedef __attribute__((ext_vector_type(8))) short bf16x8;
typedef __attribute__((ext_vector_type(4))) float f32x4;

static __device__ __forceinline__ short f2bf(float x) {
  unsigned u = __builtin_bit_cast(unsigned, x);
  unsigned r = (u + 0x7FFF + ((u >> 16) & 1)) >> 16;   // RNE
  return (short)r;
}
static __device__ __forceinline__ float bf2f(unsigned short u) {
  unsigned v = ((unsigned)u) << 16;
  return __builtin_bit_cast(float, v);
}

#define GLDS(gsrc, ldst) \
  __builtin_amdgcn_global_load_lds((const __attribute__((address_space(1))) void*)(gsrc), \
                                   (__attribute__((address_space(3))) void*)(ldst), 16, 0, 0)

// ------- fused transpose of all 4 weights fp32[K][N] -> bf16[N][2048] -------
__global__ __launch_bounds__(256)
void transpose_all(const float* __restrict__ Wq, const float* __restrict__ Wk,
                   const float* __restrict__ Wv, const float* __restrict__ Wo,
                   short* __restrict__ BTall, short* __restrict__ WoT)
{
  const int bx = blockIdx.x;
  const int k0 = blockIdx.y * 32;
  const float* src; short* dst; int Nsrc, n0;
  if (bx < 64)       { src = Wq; Nsrc = 2048; dst = BTall;                       n0 = bx * 32; }
  else if (bx < 96)  { src = Wk; Nsrc = 1024; dst = BTall + (size_t)2048 * 2048; n0 = (bx - 64) * 32; }
  else if (bx < 128) { src = Wv; Nsrc = 1024; dst = BTall + (size_t)3072 * 2048; n0 = (bx - 96) * 32; }
  else               { src = Wo; Nsrc = 2048; dst = WoT;                         n0 = (bx - 128) * 32; }

  __shared__ float tile[32][33];
  const int r = threadIdx.x >> 5, c = threadIdx.x & 31;
  #pragma unroll
  for (int i = 0; i < 4; ++i)
    tile[r + i * 8][c] = src[(size_t)(k0 + r + i * 8) * Nsrc + n0 + c];
  __syncthreads();
  const int n = threadIdx.x >> 3, k4 = (threadIdx.x & 7) * 4;
  short4 o;
  o.x = f2bf(tile[k4 + 0][n]); o.y = f2bf(tile[k4 + 1][n]);
  o.z = f2bf(tile[k4 + 2][n]); o.w = f2bf(tile[k4 + 3][n]);
  *reinterpret_cast<short4*>(&dst[(size_t)(n0 + n) * 2048 + k0 + k4]) = o;
}

// ---------------- fp32 add: out += part ----------------
__global__ __launch_bounds__(256)
void add_f32(float* __restrict__ out, const float* __restrict__ part, int n4)
{
  int i = blockIdx.x * blockDim.x + threadIdx.x;
  if (i >= n4) return;
  float4 a = reinterpret_cast<float4*>(out)[i];
  const float4 b = reinterpret_cast<const float4*>(part)[i];
  a.x += b.x; a.y += b.y; a.z += b.z; a.w += b.w;
  reinterpret_cast<float4*>(out)[i] = a;
}

// ======== bf16 MFMA GEMM: 128x128 tile, BK=32, 3-buffer counted-vmcnt ========
// m97-proven tile math (R6) + depth-2 counted prefetch (R9/R10) + 48 KB LDS so
// 2+ blocks co-reside per CU (the m114 overlap lever). Per tile t (read buf
// t%3): issue 4 staging gloads for tile t+2 into buf (t+2)%3, read fragments,
// 16 MFMA, then boundary: s_waitcnt vmcnt(4) (retires t+1's loads; t+2's 4
// stay in flight) + s_barrier. vmcnt(0) only at the tail. Race-free: buf b's
// ds_reads are consumed by pre-barrier MFMAs (lgkm-retired before the wave
// reaches the barrier); restaging of b is issued only after that barrier.
// split-K via blockIdx.z: z==0 -> Cout0 (+bias), z>0 -> Cout1 (no bias).
template <bool OBF>
__global__ __launch_bounds__(256)
void gemm3b(const short* __restrict__ A, const short* __restrict__ BT,
            const float* __restrict__ b0, const float* __restrict__ b1,
            const float* __restrict__ b2, int s1, int s2,
            void* __restrict__ Cout0, void* __restrict__ Cout1,
            int N, int Kst, int klen)
{
  __shared__ short As[3][128 * 32];
  __shared__ short Bs[3][128 * 32];
  const int tid = threadIdx.x;
  const int wave = tid >> 6, lane = tid & 63;
  const int bm0 = blockIdx.y * 128, bn0 = blockIdx.x * 128;
  const int z = blockIdx.z;
  const int koff = z * klen;
  const int wm = (wave >> 1) * 64, wn = (wave & 1) * 64;

  const int srow = wave * 32 + (lane >> 2);
  const int scol = (lane & 3) * 8;
  const short* Abase = A + (size_t)(bm0 + srow) * Kst + koff + scol;
  const short* Bbase = BT + (size_t)(bn0 + srow) * Kst + koff + scol;

  f32x4 acc[4][4] = {};
  const int nk = klen >> 5;

#define STAGE(buf, kk)                                                           \
  do {                                                                           \
    GLDS(Abase + ((kk) << 5), &As[buf][(wave * 32) * 32]);                       \
    GLDS(Abase + ((kk) << 5) + (size_t)16 * Kst, &As[buf][(wave * 32 + 16) * 32]); \
    GLDS(Bbase + ((kk) << 5), &Bs[buf][(wave * 32) * 32]);                       \
    GLDS(Bbase + ((kk) << 5) + (size_t)16 * Kst, &Bs[buf][(wave * 32 + 16) * 32]); \
  } while (0)

  // prologue: stage tiles 0 and 1; retire tile 0 only (counted), publish
  STAGE(0, 0);
  if (nk > 1) {
    STAGE(1, 1);
    asm volatile("s_waitcnt vmcnt(4)" ::: "memory");
  } else {
    asm volatile("s_waitcnt vmcnt(0)" ::: "memory");
  }
  __builtin_amdgcn_s_barrier();
  __builtin_amdgcn_sched_barrier(0);

  const int kof = (lane >> 4) * 8;
  const int rA = wm + (lane & 15);
  const int rB = wn + (lane & 15);

  for (int t = 0; t < nk; ++t) {
    const int p = t % 3, sb = (t + 2) % 3;
    if (t + 2 < nk) STAGE(sb, t + 2);

    bf16x8 af[4], bfr[4];
    #pragma unroll
    for (int i = 0; i < 4; ++i) {
      af[i]  = *reinterpret_cast<const bf16x8*>(&As[p][(rA + i * 16) * 32 + kof]);
      bfr[i] = *reinterpret_cast<const bf16x8*>(&Bs[p][(rB + i * 16) * 32 + kof]);
    }
    #pragma unroll
    for (int i = 0; i < 4; ++i)
      #pragma unroll
      for (int j = 0; j < 4; ++j)
        acc[i][j] = __builtin_amdgcn_mfma_f32_16x16x32_bf16(af[i], bfr[j], acc[i][j], 0, 0, 0);

    if (t + 1 < nk) {
      __builtin_amdgcn_sched_barrier(0);   // pin MFMAs before the boundary
      if (t + 2 < nk) asm volatile("s_waitcnt vmcnt(4)" ::: "memory");
      else            asm volatile("s_waitcnt vmcnt(0)" ::: "memory");
      __builtin_amdgcn_s_barrier();
      __builtin_amdgcn_sched_barrier(0);
    }
  }

  void* Cout = z ? Cout1 : Cout0;
  const int crow = wm + (lane >> 4) * 4;
  const int ccol = wn + (lane & 15);
  #pragma unroll
  for (int j = 0; j < 4; ++j) {
    const int col = bn0 + ccol + j * 16;
    float b = 0.f;
    if (z == 0)
      b = (col < s1) ? b0[col] : ((col < s2) ? b1[col - s1] : b2[col - s2]);
    #pragma unroll
    for (int i = 0; i < 4; ++i)
      #pragma unroll
      for (int r = 0; r < 4; ++r) {
        const int row = bm0 + crow + i * 16 + r;
        const float v = acc[i][j][r] + b;
        if constexpr (OBF)
          ((short*)Cout)[(size_t)row * N + col] = f2bf(v);
        else
          ((float*)Cout)[(size_t)row * N + col] = v;
      }
  }
#undef STAGE
}

// ---- gate projection + log-sigmoid, fused with hs -> bf16 conversion ----
__global__ __launch_bounds__(256)
void gproj_kernel(const float* __restrict__ hs, const float* __restrict__ Wg,
                  const float* __restrict__ bg, float* __restrict__ gT,
                  short* __restrict__ hsb)
{
  const int t = blockIdx.x, tid = threadIdx.x;
  __shared__ float red[256][9];
  float a[8] = {0.f, 0.f, 0.f, 0.f, 0.f, 0.f, 0.f, 0.f};
  for (int cc = tid; cc < HID; cc += 256) {
    const float hv = hs[(size_t)t * HID + cc];
    hsb[(size_t)t * HID + cc] = f2bf(hv);        // fused bf16 conversion
    const float4 w0 = *reinterpret_cast<const float4*>(Wg + (size_t)cc * 8);
    const float4 w1 = *reinterpret_cast<const float4*>(Wg + (size_t)cc * 8 + 4);
    a[0] = fmaf(hv, w0.x, a[0]); a[1] = fmaf(hv, w0.y, a[1]);
    a[2] = fmaf(hv, w0.z, a[2]); a[3] = fmaf(hv, w0.w, a[3]);
    a[4] = fmaf(hv, w1.x, a[4]); a[5] = fmaf(hv, w1.y, a[5]);
    a[6] = fmaf(hv, w1.z, a[6]); a[7] = fmaf(hv, w1.w, a[7]);
  }
  #pragma unroll
  for (int j = 0; j < 8; ++j) red[tid][j] = a[j];
  __syncthreads();
  for (int s = 128; s >= 1; s >>= 1) {
    if (tid < s) {
      #pragma unroll
      for (int j = 0; j < 8; ++j) red[tid][j] += red[tid + s][j];
    }
    __syncthreads();
  }
  if (tid < 8) {
    const float x = red[0][tid] + bg[tid];
    const float nx = -x;
    const float sp = (nx > 20.f) ? nx : log1pf(expf(nx));
    gT[(size_t)tid * T_SEQ + t] = -sp;      // log_sigmoid(x)
  }
}

// ------- parallel inclusive cumsum over T per head -------
__global__ __launch_bounds__(512)
void gscan_kernel(const float* __restrict__ gT, float* __restrict__ Gct)
{
  const int h = blockIdx.x;
  const int tid = threadIdx.x;
  const int wid = tid >> 6, lane = tid & 63;
  __shared__ float wsum[8];

  const float4 v = reinterpret_cast<const float4*>(gT + (size_t)h * T_SEQ)[tid];
  const float p0 = v.x, p1 = p0 + v.y, p2 = p1 + v.z, p3 = p2 + v.w;

  float sc = p3;
  #pragma unroll
  for (int off = 1; off < 64; off <<= 1) {
    const float o = __shfl_up(sc, off, 64);
    if (lane >= off) sc += o;
  }
  if (lane == 63) wsum[wid] = sc;
  __syncthreads();
  float wof = 0.f;
  #pragma unroll
  for (int w = 0; w < 8; ++w) wof += (w < wid) ? wsum[w] : 0.f;

  const float excl = wof + sc - p3;
  reinterpret_cast<float4*>(Gct + (size_t)h * T_SEQ)[tid] =
      make_float4(excl + p0, excl + p1, excl + p2, excl + p3);
}

// ---- fused RoPE (blocks 0..2047) + V transpose (blocks 2048..4095) ----
__global__ __launch_bounds__(256)
void rope_vtrans(short* __restrict__ proj, unsigned short* __restrict__ vt)
{
  __shared__ float cs[64], sn[64];
  __shared__ unsigned short tile[32][33];

  if (blockIdx.x < 2048) {
    const int t = blockIdx.x;
    if (threadIdx.x < 64) {
      const int i = threadIdx.x;
      const float f = (float)t * powf(10000.0f, -(float)i / 64.0f);
      cs[i] = cosf(f); sn[i] = sinf(f);
    }
    __syncthreads();
    const int u = threadIdx.x;          // 24 heads x 8 chunks (192 active)
    if (u < 192) {
      const int hh = u >> 3, ch = u & 7;
      short* base = proj + (size_t)t * PROJW +
                    ((hh < HQ) ? hh * D_HEAD : 2048 + (hh - HQ) * D_HEAD);
      bf16x8 x1 = *reinterpret_cast<bf16x8*>(base + ch * 8);
      bf16x8 x2 = *reinterpret_cast<bf16x8*>(base + HALF + ch * 8);
      #pragma unroll
      for (int j = 0; j < 8; ++j) {
        const float a = bf2f((unsigned short)x1[j]);
        const float b = bf2f((unsigned short)x2[j]);
        const float cc = cs[ch * 8 + j], ss = sn[ch * 8 + j];
        x1[j] = f2bf(a * cc - b * ss);
        x2[j] = f2bf(b * cc + a * ss);
      }
      *reinterpret_cast<bf16x8*>(base + ch * 8) = x1;
      *reinterpret_cast<bf16x8*>(base + HALF + ch * 8) = x2;
    }
  } else {
    const int idx = blockIdx.x - 2048;
    const int tt = (idx & 63) * 32, dd = ((idx >> 6) & 3) * 32, hk = idx >> 8;
    const unsigned short* pj = (const unsigned short*)proj;
    const int c = threadIdx.x & 31, r0 = (threadIdx.x >> 5) * 4;
    #pragma unroll
    for (int i = 0; i < 4; ++i)
      tile[r0 + i][c] = pj[(size_t)(tt + r0 + i) * PROJW + 3072 + hk * 128 + dd + c];
    __syncthreads();
    #pragma unroll
    for (int i = 0; i < 4; ++i)
      vt[(size_t)(hk * 128 + dd + r0 + i) * T_SEQ + tt + c] = tile[c][r0 + i];
  }
}

// ---------------- MFMA attention ----------------
__global__ __launch_bounds__(256, 1)
void attn_mfma(const short* __restrict__ proj, const short* __restrict__ vt,
               const float* __restrict__ Gct, short* __restrict__ outb)
{
  __shared__ __align__(16) char smem[86528];
  const int hk = blockIdx.x;
  const int tb = blockIdx.y * 64;
  const int tid = threadIdx.x;
  const int wid = tid >> 6, lane = tid & 63;
  const int c = lane & 15, g = lane >> 4;
  const int h = 2 * hk + (wid >> 1);
  const int tw = tb + (wid & 1) * 32;
  const float* Gh = Gct + (size_t)hk * T_SEQ;

  const float glim = Gh[tb] + 90.0f;
  int lo = 0, hi = tb;
  while (lo < hi) {
    const int mid = (lo + hi) >> 1;
    if (Gh[mid] > glim) lo = mid + 1; else hi = mid;
  }
  const int sfirst = lo & ~63;
  const int nst = ((tb - sfirst) >> 6) + 1;

  bf16x8 qf[2][4];
  #pragma unroll
  for (int tt = 0; tt < 2; ++tt)
    #pragma unroll
    for (int kb = 0; kb < 4; ++kb)
      qf[tt][kb] = *reinterpret_cast<const bf16x8*>(
          proj + (size_t)(tw + 16 * tt + c) * PROJW + h * D_HEAD + kb * 32 + g * 8);
  const float gt0 = Gh[tw + c];
  const float gt1 = Gh[tw + 16 + c];
  const float gtw = Gh[tw];
  const int twmax = tw + 31;

  f32x4 accv[2][8] = {};

#define ASTG(buf, s64)                                                                   \
  do {                                                                                   \
    _Pragma("unroll")                                                                    \
    for (int i2 = 0; i2 < 4; ++i2) {                                                     \
      const int cid = tid + 256 * i2;                                                    \
      const int kr = cid >> 4, kc = cid & 15;                                            \
      GLDS(proj + (size_t)((s64) + kr) * PROJW + 2048 + hk * 128 + ((kc ^ (kr & 7)) * 8),\
           smem + (buf) * 16384 + cid * 16);                                             \
      const int vr = cid >> 3, vc = cid & 7;                                             \
      GLDS(vt + (size_t)(hk * 128 + vr) * T_SEQ + (s64) + ((vc ^ (vr & 7)) * 8),         \
           smem + 32768 + (buf) * 16384 + cid * 16);                                     \
    }                                                                                    \
    if (tid < 64) ((float*)(smem + 86016))[(buf) * 64 + tid] = Gh[(s64) + tid];          \
  } while (0)

  ASTG(0, sfirst);
  __syncthreads();

  for (int i = 0; i < nst; ++i) {
    const int cur = i & 1;
    if (i + 1 < nst) ASTG(cur ^ 1, sfirst + (i + 1) * 64);
    const int sbase64 = sfirst + i * 64;
    const float* Gss = (const float*)(smem + 86016) + cur * 64;
    char* Pmy = smem + 65536 + wid * 5120;

    #pragma unroll
    for (int st = 0; st < 2; ++st) {
      const int s0 = sbase64 + st * 32;
      if (s0 > twmax) continue;
      if (gtw - Gss[st * 32 + 31] < -90.0f) continue;

      bf16x8 kf[2][4];
      #pragma unroll
      for (int sg = 0; sg < 2; ++sg)
        #pragma unroll
        for (int kb = 0; kb < 4; ++kb) {
          const int row = st * 32 + 16 * sg + c;
          const int byt = (row * 256 + kb * 64 + g * 16) ^ ((c & 7) << 4);
          kf[sg][kb] = *reinterpret_cast<const bf16x8*>(smem + cur * 16384 + byt);
        }
      f32x4 sa[2][2] = {};
      #pragma unroll
      for (int kb = 0; kb < 4; ++kb)
        #pragma unroll
        for (int sg = 0; sg < 2; ++sg)
          #pragma unroll
          for (int tt = 0; tt < 2; ++tt)
            sa[sg][tt] = __builtin_amdgcn_mfma_f32_16x16x32_bf16(
                kf[sg][kb], qf[tt][kb], sa[sg][tt], 0, 0, 0);

      #pragma unroll
      for (int sg = 0; sg < 2; ++sg) {
        const float4 gs = *reinterpret_cast<const float4*>(&Gss[st * 32 + sg * 16 + g * 4]);
        const float gsv[4] = {gs.x, gs.y, gs.z, gs.w};
        #pragma unroll
        for (int tt = 0; tt < 2; ++tt) {
          const int tg = tw + 16 * tt + c;
          const float gt = tt ? gt1 : gt0;
          const int sg0 = s0 + sg * 16 + g * 4;
          float w[4];
          #pragma unroll
          for (int r = 0; r < 4; ++r) {
            const float dv = sa[sg][tt][r] * SCALE_F;
            const float ww = dv * dv * __expf(gt - gsv[r]);
            w[r] = (sg0 + r <= tg) ? ww : 0.0f;
          }
          uint2 pv;
          pv.x = ((unsigned)(unsigned short)f2bf(w[1]) << 16) | (unsigned short)f2bf(w[0]);
          pv.y = ((unsigned)(unsigned short)f2bf(w[3]) << 16) | (unsigned short)f2bf(w[2]);
          *reinterpret_cast<uint2*>(Pmy + st * 2560 + (c + 16 * tt) * 80 + 8 * g + 32 * sg) = pv;
        }
      }
      asm volatile("s_waitcnt lgkmcnt(0)" ::: "memory");
      __builtin_amdgcn_sched_barrier(0);

      bf16x8 pf[2];
      #pragma unroll
      for (int tt = 0; tt < 2; ++tt)
        pf[tt] = *reinterpret_cast<const bf16x8*>(Pmy + st * 2560 + (c + 16 * tt) * 80 + g * 16);

      #pragma unroll
      for (int db = 0; db < 8; ++db) {
        const int row = 16 * db + c;
        const int byt = (row * 128 + st * 64 + g * 16) ^ ((c & 7) << 4);
        const bf16x8 vf = *reinterpret_cast<const bf16x8*>(smem + 32768 + cur * 16384 + byt);
        #pragma unroll
        for (int tt = 0; tt < 2; ++tt)
          accv[tt][db] = __builtin_amdgcn_mfma_f32_16x16x32_bf16(pf[tt], vf, accv[tt][db], 0, 0, 0);
      }
    }
    __syncthreads();
  }

  char* Wme = smem + wid * 8704;
  #pragma unroll
  for (int tt = 0; tt < 2; ++tt)
    #pragma unroll
    for (int db = 0; db < 8; ++db)
      #pragma unroll
      for (int r = 0; r < 4; ++r)
        *reinterpret_cast<short*>(Wme + (16 * tt + 4 * g + r) * 272 + (16 * db + c) * 2)
            = f2bf(accv[tt][db][r]);
  asm volatile("s_waitcnt lgkmcnt(0)" ::: "memory");
  __builtin_amdgcn_sched_barrier(0);
  #pragma unroll
  for (int e = 0; e < 8; ++e) {
    const int idx = e * 64 + lane;
    const int tr = idx >> 4, d0 = (idx & 15) * 8;
    const bf16x8 vv = *reinterpret_cast<const bf16x8*>(Wme + tr * 272 + d0 * 2);
    *reinterpret_cast<bf16x8*>(outb + ((size_t)(tw + tr) * HQ + h) * D_HEAD + d0) = vv;
  }
#undef ASTG
}

extern "C" void kernel_launch(void* const* d_in, const int* in_sizes, int n_in,
                              void* d_out, int out_size, void* d_ws, size_t ws_size,
                              hipStream_t stream)
{
  const float* hs = (const float*)d_in[1];
  const float* Wq = (const float*)d_in[2];
  const float* bq = (const float*)d_in[3];
  const float* Wk = (const float*)d_in[4];
  const float* bk = (const float*)d_in[5];
  const float* Wv = (const float*)d_in[6];
  const float* bv = (const float*)d_in[7];
  const float* Wg = (const float*)d_in[8];
  const float* bg = (const float*)d_in[9];
  const float* Wo = (const float*)d_in[10];
  const float* bo = (const float*)d_in[11];
  float* outp = (float*)d_out;

  // workspace carve (~52.2 MB)
  short* proj  = (short*)d_ws;                    // [T][4096] bf16 (q|k|v)   16 MB
  short* vtb   = proj + (size_t)T_SEQ * PROJW;    // [8][128][T] bf16          4 MB
  float* gT    = (float*)(vtb + (size_t)HKV * D_HEAD * T_SEQ);
  float* Gct   = gT + 16384;
  short* hsb   = (short*)(Gct + 16384);           // [T][2048] bf16            8 MB
  short* BTall = hsb + (size_t)2048 * 2048;       // [4096][2048] bf16        16 MB
  short* WoT   = BTall + (size_t)4096 * 2048;     // [2048][2048] bf16         8 MB
  short* attnout = hsb;                           // alias: hsb dead after QKV GEMM
  float* opart   = (float*)BTall;                 // alias: BTall dead after QKV GEMM

  // 1) weight transposes
  transpose_all<<<dim3(192, 64), 256, 0, stream>>>(Wq, Wk, Wv, Wo, BTall, WoT);

  // 2) gate projection (+ fused hs->bf16) and cumsum scan
  gproj_kernel<<<2048, 256, 0, stream>>>(hs, Wg, bg, gT, hsb);
  gscan_kernel<<<8, 512, 0, stream>>>(gT, Gct);

  // 3) fused QKV projection: 128x128 tiles, 32x16 = 512 blocks (2/CU)
  gemm3b<true><<<dim3(32, 16, 1), 256, 0, stream>>>(
      hsb, BTall, bq, bk, bv, 2048, 3072, proj, proj, PROJW, 2048, 2048);

  // 4) fused RoPE + V transpose (one dispatch)
  rope_vtrans<<<4096, 256, 0, stream>>>(proj, (unsigned short*)vtb);

  // 5) attention -> bf16 into hsb region
  attn_mfma<<<dim3(8, 32), 256, 0, stream>>>(proj, vtb, Gct, attnout);

  // 6) output projection, split-K=2: 16x16x2 = 512 blocks (2/CU)
  gemm3b<false><<<dim3(16, 16, 2), 256, 0, stream>>>(
      attnout, WoT, bo, bo, bo, 1 << 30, 1 << 30, outp, opart, 2048, 2048, 1024);
  add_f32<<<4096, 256, 0, stream>>>(outp, opart, 1048576);
}